// Round 2
// baseline (316.459 us; speedup 1.0000x reference)
//
#include <hip/hip_runtime.h>

// Masked self-attention, B=4 T=2048 C=1024 (single head, head dim = C).
// All GEMMs on a 256x256 / BK=64 / 8-wave 8-phase pipelined bf16 MFMA kernel
// (counted vmcnt, st_16x32 LDS swizzle, setprio) per the m201 template.
//   1. cvt: x -> xb bf16; Wq|Wk|Wv packed -> Wqkvb; Wo -> Wob; biases packed.
//   2. gemm8<QKV>:  [Q|K] -> QK [8192][2048], V -> Vt[b][c][t] (transposed)
//   3. gemm8<BF16,SKIP>: S = Q K^T / 32   (bf16, lower-triangle blocks only)
//   4. softmax_causal in-place: S -> P (exact zeros above diagonal)
//   5. gemm8<BF16,CLAMP>: attn = P @ V   (K clamped to m0+256; reuses xb)
//   6. gemm8<F32>: out = attn Wo^T + bo

typedef __attribute__((ext_vector_type(8))) short short8;
typedef __attribute__((ext_vector_type(4))) float f32x4;
typedef __attribute__((ext_vector_type(4))) unsigned short us4;
typedef __attribute__((ext_vector_type(8))) unsigned short us8;
typedef __attribute__((ext_vector_type(4))) float fl4;

__device__ __forceinline__ unsigned short f2b(float f) {
  unsigned int u = __builtin_bit_cast(unsigned int, f);
  u += 0x7fffu + ((u >> 16) & 1u);   // round-to-nearest-even
  return (unsigned short)(u >> 16);
}
__device__ __forceinline__ float b2f(unsigned short h) {
  unsigned int u = ((unsigned int)h) << 16;
  return __builtin_bit_cast(float, u);
}
__device__ __forceinline__ int swz(int x) { return x ^ (((x >> 9) & 1) << 5); }

// ---------------- fp32 -> bf16 convert ----------------
__global__ __launch_bounds__(256) void cvt_kernel(const float* __restrict__ src,
                                                  unsigned short* __restrict__ dst,
                                                  int n4) {
  int i = blockIdx.x * blockDim.x + threadIdx.x;
  if (i < n4) {
    fl4 f = *(const fl4*)&src[(size_t)i << 2];
    us4 o;
#pragma unroll
    for (int j = 0; j < 4; ++j) o[j] = f2b(f[j]);
    *(us4*)&dst[(size_t)i << 2] = o;
  }
}

__global__ __launch_bounds__(256) void bias_copy(const float* bq, const float* bk,
                                                 const float* bv, const float* bo,
                                                 float* dst) {
  int i = blockIdx.x * 256 + threadIdx.x;   // grid 16 -> 4096
  int sel = i >> 10, idx = i & 1023;
  const float* p = sel == 0 ? bq : sel == 1 ? bk : sel == 2 ? bv : bo;
  dst[i] = p[idx];
}

// ---------------- 256x256 8-phase pipelined B^T GEMM ----------------
// C[m][n] = scale * sum_k A[m][k]*B[n][k] (+bias). A,B bf16 k-contiguous.
// 512 threads = 8 waves (2M x 4N). LDS: 2dbuf x 2half x 128x64 x (A,B) = 128KB.
// Quadrant order (mh,nh): (0,0),(1,0),(1,1),(0,1).
// Stage per phase: q0: B[t+1]h1, q1: A[t+1]h0, q2: B[t+2]h0, q3: A[t+2]h1.
// vmcnt(4) at q3 == next tile fully landed, 2 half-tiles (4 loads) in flight.
// EPI: 0 = QKV split (cols<2048 -> QK + bias, cols>=2048 -> Vt transposed + bias)
//      1 = bf16 out, scale      2 = f32 out, scale + bias

template<int Q, int MH, int NH, class FA, class FB>
__device__ __forceinline__ void phase8(int t, int buf,
    f32x4 (&acc)[2][4][2][2], const int (&offA)[4][2], const int (&offB)[2][2],
    unsigned short (&lA)[2][2][8192], unsigned short (&lB)[2][2][8192],
    FA& stA, FB& stB)
{
  short8 af[4][2], bf2[2][2];
  const char* Ah = (const char*)&lA[buf][MH][0];
  const char* Bh = (const char*)&lB[buf][NH][0];
#pragma unroll
  for (int mi = 0; mi < 4; ++mi)
#pragma unroll
    for (int ks = 0; ks < 2; ++ks)
      af[mi][ks] = *(const short8*)(Ah + offA[mi][ks]);
#pragma unroll
  for (int nj = 0; nj < 2; ++nj)
#pragma unroll
    for (int ks = 0; ks < 2; ++ks)
      bf2[nj][ks] = *(const short8*)(Bh + offB[nj][ks]);

  if (Q == 0)      stB((t + 1) & 1, 1, t + 1);
  else if (Q == 1) stA((t + 1) & 1, 0, t + 1);
  else if (Q == 2) stB(buf, 0, t + 2);
  else { stA(buf, 1, t + 2);
         asm volatile("s_waitcnt vmcnt(4)" ::: "memory"); }

  __builtin_amdgcn_s_barrier();
  asm volatile("s_waitcnt lgkmcnt(0)" ::: "memory");
  __builtin_amdgcn_s_setprio(1);
#pragma unroll
  for (int ks = 0; ks < 2; ++ks)
#pragma unroll
    for (int mi = 0; mi < 4; ++mi)
#pragma unroll
      for (int nj = 0; nj < 2; ++nj)
        acc[MH][mi][NH][nj] = __builtin_amdgcn_mfma_f32_16x16x32_bf16(
            af[mi][ks], bf2[nj][ks], acc[MH][mi][NH][nj], 0, 0, 0);
  __builtin_amdgcn_s_setprio(0);
  __builtin_amdgcn_s_barrier();
}

template<int EPI, bool CLAMP_K, bool SKIP_UPPER>
__global__ __launch_bounds__(512, 2)
void gemm8(const unsigned short* __restrict__ A, const unsigned short* __restrict__ B,
           void* __restrict__ Cout, unsigned short* __restrict__ Vt,
           const float* __restrict__ bias, float scale, int K,
           int lda, int ldb, int ldc,
           long long sAz, long long sBz, long long sCz)
{
  const int m0 = blockIdx.y << 8;
  const int n0 = blockIdx.x << 8;
  if (SKIP_UPPER && n0 > m0 + 255) return;   // fully-masked score block
  const int z = blockIdx.z;

  __shared__ unsigned short lA[2][2][8192];  // [dbuf][half][128*64]
  __shared__ unsigned short lB[2][2][8192];

  const int tid = threadIdx.x, lane = tid & 63, wid = tid >> 6;
  const int wm = wid >> 2, wn = wid & 3;     // 2 x 4 waves
  const int fr = lane & 15, kg = lane >> 4;

  int kEnd = K;
  if (CLAMP_K) kEnd = (m0 + 256 < K) ? m0 + 256 : K;   // causal PV clamp
  const int nt = kEnd >> 6;

  const unsigned short* Ab = A + (size_t)z * sAz;
  const unsigned short* Bb = B + (size_t)z * sBz;

  // staging: thread covers dest off = c*8192 + tid*16 bytes within a half;
  // source column pre-swizzled (inverse of read swizzle; XOR is involution)
  const int srow = tid >> 3;                                 // + c*64
  const int scolb = ((tid & 7) << 4) ^ (((tid >> 5) & 1) << 5);
  const unsigned short* aSrc = Ab + (size_t)(m0 + srow) * lda + (scolb >> 1);
  const unsigned short* bSrc = Bb + (size_t)(n0 + srow) * ldb + (scolb >> 1);

  auto stA = [&](int buf, int h, int tt) {
    int ttc = tt < nt ? tt : nt - 1;         // tail: valid-addr dummy stage
    const unsigned short* s0 = aSrc + (size_t)(h * 128) * lda + (ttc << 6);
#pragma unroll
    for (int c = 0; c < 2; ++c)
      __builtin_amdgcn_global_load_lds(
          (const __attribute__((address_space(1))) void*)(s0 + (size_t)(c * 64) * lda),
          (__attribute__((address_space(3))) void*)((char*)&lA[buf][h][0] + (c << 13) + (wid << 10)),
          16, 0, 0);
  };
  auto stB = [&](int buf, int h, int tt) {
    int ttc = tt < nt ? tt : nt - 1;
    const unsigned short* s0 = bSrc + (size_t)(h * 128) * ldb + (ttc << 6);
#pragma unroll
    for (int c = 0; c < 2; ++c)
      __builtin_amdgcn_global_load_lds(
          (const __attribute__((address_space(1))) void*)(s0 + (size_t)(c * 64) * ldb),
          (__attribute__((address_space(3))) void*)((char*)&lB[buf][h][0] + (c << 13) + (wid << 10)),
          16, 0, 0);
  };

  f32x4 acc[2][4][2][2];
#pragma unroll
  for (int a = 0; a < 2; ++a)
#pragma unroll
    for (int b = 0; b < 4; ++b)
#pragma unroll
      for (int c = 0; c < 2; ++c)
#pragma unroll
        for (int d = 0; d < 2; ++d)
          acc[a][b][c][d] = f32x4{0.f, 0.f, 0.f, 0.f};

  int offA[4][2], offB[2][2];
#pragma unroll
  for (int mi = 0; mi < 4; ++mi)
#pragma unroll
    for (int ks = 0; ks < 2; ++ks)
      offA[mi][ks] = swz(((wm * 64 + mi * 16 + fr) << 7) + (ks << 6) + (kg << 4));
#pragma unroll
  for (int nj = 0; nj < 2; ++nj)
#pragma unroll
    for (int ks = 0; ks < 2; ++ks)
      offB[nj][ks] = swz(((wn * 32 + nj * 16 + fr) << 7) + (ks << 6) + (kg << 4));

  // prologue: matches steady-state issue tail; tile0 complete after vmcnt(4)
  stB(0, 0, 0); stA(0, 1, 0); stB(0, 1, 0); stA(0, 0, 0); stB(1, 0, 1); stA(1, 1, 1);
  asm volatile("s_waitcnt vmcnt(4)" ::: "memory");
  __builtin_amdgcn_s_barrier();

  for (int t = 0; t < nt; ++t) {
    const int buf = t & 1;
    phase8<0, 0, 0>(t, buf, acc, offA, offB, lA, lB, stA, stB);
    phase8<1, 1, 0>(t, buf, acc, offA, offB, lA, lB, stA, stB);
    phase8<2, 1, 1>(t, buf, acc, offA, offB, lA, lB, stA, stB);
    phase8<3, 0, 1>(t, buf, acc, offA, offB, lA, lB, stA, stB);
  }

  // epilogue: C frag layout col=lane&15, row=(lane>>4)*4+reg
#pragma unroll
  for (int mh = 0; mh < 2; ++mh)
#pragma unroll
    for (int mi = 0; mi < 4; ++mi)
#pragma unroll
      for (int nh = 0; nh < 2; ++nh)
#pragma unroll
        for (int nj = 0; nj < 2; ++nj) {
          const int row = m0 + mh * 128 + wm * 64 + mi * 16 + (kg << 2);
          const int col = n0 + nh * 128 + wn * 32 + nj * 16 + fr;
          f32x4 v = acc[mh][mi][nh][nj];
          if (EPI == 0) {
            const float bb = bias[col];
            if (col < 2048) {
              unsigned short* Ch = (unsigned short*)Cout;
#pragma unroll
              for (int jj = 0; jj < 4; ++jj)
                Ch[(size_t)(row + jj) * 2048 + col] = f2b(v[jj] + bb);
            } else {
              const int batch = row >> 11, t0 = row & 2047, cc = col - 2048;
              us4 o;
#pragma unroll
              for (int jj = 0; jj < 4; ++jj) o[jj] = f2b(v[jj] + bb);
              *(us4*)&Vt[(size_t)batch * (1024 * 2048) + (size_t)cc * 2048 + t0] = o;
            }
          } else if (EPI == 1) {
            unsigned short* Ch = (unsigned short*)Cout + (size_t)z * sCz;
#pragma unroll
            for (int jj = 0; jj < 4; ++jj)
              Ch[(size_t)(row + jj) * ldc + col] = f2b(v[jj] * scale);
          } else {
            float* Cf = (float*)Cout + (size_t)z * sCz;
            const float bb = bias[col];
#pragma unroll
            for (int jj = 0; jj < 4; ++jj)
              Cf[(size_t)(row + jj) * ldc + col] = v[jj] * scale + bb;
          }
        }
}

// ---------------- causal softmax, in-place over bf16 rows ----------------
__global__ __launch_bounds__(256)
void softmax_causal(unsigned short* __restrict__ S, int T) {
  const int t = blockIdx.x, b = blockIdx.y;
  unsigned short* row = S + ((size_t)b * T + t) * T;
  const int tid  = threadIdx.x;
  const int lane = tid & 63;
  const int wid  = tid >> 6;
  const int base = tid << 3;   // 256 threads * 8 = 2048

  us8 raw = *(const us8*)&row[base];
  float v[8];
  float mx = -3.0e38f;
#pragma unroll
  for (int j = 0; j < 8; ++j) {
    const int s = base + j;
    v[j] = (s <= t) ? b2f(raw[j]) : -3.0e38f;
    mx = fmaxf(mx, v[j]);
  }
#pragma unroll
  for (int m = 32; m; m >>= 1) mx = fmaxf(mx, __shfl_xor(mx, m, 64));
  __shared__ float red[4];
  if (lane == 0) red[wid] = mx;
  __syncthreads();
  mx = fmaxf(fmaxf(red[0], red[1]), fmaxf(red[2], red[3]));

  float e[8];
  float sum = 0.f;
#pragma unroll
  for (int j = 0; j < 8; ++j) { e[j] = __expf(v[j] - mx); sum += e[j]; }
#pragma unroll
  for (int m = 32; m; m >>= 1) sum += __shfl_xor(sum, m, 64);
  __syncthreads();
  if (lane == 0) red[wid] = sum;
  __syncthreads();
  sum = red[0] + red[1] + red[2] + red[3];
  const float inv = 1.f / sum;

  us8 o;
#pragma unroll
  for (int j = 0; j < 8; ++j) o[j] = f2b(e[j] * inv);
  *(us8*)&row[base] = o;
}

// ---------------- host-side launch ----------------
extern "C" void kernel_launch(void* const* d_in, const int* in_sizes, int n_in,
                              void* d_out, int out_size, void* d_ws, size_t ws_size,
                              hipStream_t stream) {
  (void)in_sizes; (void)n_in; (void)out_size; (void)ws_size;
  const float* x  = (const float*)d_in[0];
  const float* Wq = (const float*)d_in[1];
  const float* bq = (const float*)d_in[2];
  const float* Wk = (const float*)d_in[3];
  const float* bk = (const float*)d_in[4];
  const float* Wv = (const float*)d_in[5];
  const float* bv = (const float*)d_in[6];
  const float* Wo = (const float*)d_in[7];
  const float* bo = (const float*)d_in[8];

  const int B = 4, T = 2048, C = 1024;
  const int M = B * T;                                   // 8192

  unsigned short* xb    = (unsigned short*)d_ws;         // M*C (later reused as attn)
  unsigned short* Wqkvb = xb    + (size_t)M * C;         // 3C*C packed [Wq|Wk|Wv]
  unsigned short* Wob   = Wqkvb + (size_t)3 * C * C;     // C*C
  unsigned short* QK    = Wob   + (size_t)C * C;         // M*2C  [Q|K]
  unsigned short* VtB   = QK    + (size_t)M * 2 * C;     // B*C*T  [b][c][t]
  unsigned short* S     = VtB   + (size_t)M * C;         // B*T*T (becomes P)
  float*          bws   = (float*)(S + (size_t)B * T * T); // 4096: bq|bk|bv|bo
  unsigned short* attn  = xb;

  // 1. converts + packing
  cvt_kernel<<<M * C / 4 / 256, 256, 0, stream>>>(x, xb, M * C / 4);
  cvt_kernel<<<C * C / 4 / 256, 256, 0, stream>>>(Wq, Wqkvb, C * C / 4);
  cvt_kernel<<<C * C / 4 / 256, 256, 0, stream>>>(Wk, Wqkvb + (size_t)C * C, C * C / 4);
  cvt_kernel<<<C * C / 4 / 256, 256, 0, stream>>>(Wv, Wqkvb + (size_t)2 * C * C, C * C / 4);
  cvt_kernel<<<C * C / 4 / 256, 256, 0, stream>>>(Wo, Wob, C * C / 4);
  bias_copy<<<16, 256, 0, stream>>>(bq, bk, bv, bo, bws);

  // 2. fused QKV projection: [Q|K] -> QK, V -> Vt (transposed)
  gemm8<0, false, false><<<dim3(3 * C / 256, M / 256, 1), 512, 0, stream>>>(
      xb, Wqkvb, QK, VtB, bws, 1.f, C, C, C, 0, 0LL, 0LL, 0LL);

  // 3. scores: S = Q K^T / 32 (bf16), lower-triangle 256-blocks only
  gemm8<1, false, true><<<dim3(T / 256, T / 256, B), 512, 0, stream>>>(
      QK, QK + C, S, nullptr, nullptr, 0.03125f, C, 2 * C, 2 * C, T,
      (long long)T * 2 * C, (long long)T * 2 * C, (long long)T * T);

  // 4. causal softmax in-place (writes zeros above diagonal)
  softmax_causal<<<dim3(T, B), 256, 0, stream>>>(S, T);

  // 5. attn = P @ V (B-operand Vt[b][c][s], K causally clamped)
  gemm8<1, true, false><<<dim3(C / 256, T / 256, B), 512, 0, stream>>>(
      S, VtB, attn, nullptr, nullptr, 1.f, T, T, T, C,
      (long long)T * T, (long long)C * T, (long long)T * C);

  // 6. out = attn Wo^T + bo (fp32)
  gemm8<2, false, false><<<dim3(C / 256, M / 256, 1), 512, 0, stream>>>(
      attn, Wob, d_out, nullptr, bws + 3 * C, 1.f, C, C, C, C, 0LL, 0LL, 0LL);
}

// Round 4
// 218.753 us; speedup vs baseline: 1.4466x; 1.4466x over previous
//
#include <hip/hip_runtime.h>

// Masked self-attention, B=4 T=2048 C=1024 (single head, head dim = C).
// 256x256 / BK=64 / 8-wave register-resident 8-phase bf16 MFMA GEMM (m201
// template): per K-tile each wave reads its fragments ONCE (12+8+4+0
// ds_read_b128), holds them in registers, MFMA quadrants reuse them.
// LDS swizzle: slot ^= (row&7) on 16B slots of 128B rows, applied both-sides
// (inverse-swizzled global_load_lds source + full-slot-XOR ds_read offsets).
// Counted vmcnt(4) once per K-tile; setprio around MFMA clusters;
// sched_barrier(0) after each lgkmcnt(0) (rule 18).

typedef __attribute__((ext_vector_type(8))) short short8;
typedef __attribute__((ext_vector_type(4))) float f32x4;
typedef __attribute__((ext_vector_type(4))) unsigned short us4;
typedef __attribute__((ext_vector_type(8))) unsigned short us8;
typedef __attribute__((ext_vector_type(4))) float fl4;

__device__ __forceinline__ unsigned short f2b(float f) {
  unsigned int u = __builtin_bit_cast(unsigned int, f);
  u += 0x7fffu + ((u >> 16) & 1u);   // round-to-nearest-even
  return (unsigned short)(u >> 16);
}
__device__ __forceinline__ float b2f(unsigned short h) {
  unsigned int u = ((unsigned int)h) << 16;
  return __builtin_bit_cast(float, u);
}

// ---------------- fp32 -> bf16 converts ----------------
__global__ __launch_bounds__(256) void cvt_kernel(const float* __restrict__ src,
                                                  unsigned short* __restrict__ dst,
                                                  int n4) {
  int i = blockIdx.x * blockDim.x + threadIdx.x;
  if (i < n4) {
    fl4 f = *(const fl4*)&src[(size_t)i << 2];
    us4 o;
#pragma unroll
    for (int j = 0; j < 4; ++j) o[j] = f2b(f[j]);
    *(us4*)&dst[(size_t)i << 2] = o;
  }
}

__global__ __launch_bounds__(256) void cvt4_kernel(
    const float* s0, const float* s1, const float* s2, const float* s3,
    unsigned short* d0, unsigned short* d1, unsigned short* d2, unsigned short* d3,
    int n4) {
  int i = blockIdx.x * 256 + threadIdx.x;
  if (i >= n4) return;
  int w = blockIdx.y;
  const float* s = w == 0 ? s0 : w == 1 ? s1 : w == 2 ? s2 : s3;
  unsigned short* d = w == 0 ? d0 : w == 1 ? d1 : w == 2 ? d2 : d3;
  fl4 f = *(const fl4*)&s[(size_t)i << 2];
  us4 o;
#pragma unroll
  for (int j = 0; j < 4; ++j) o[j] = f2b(f[j]);
  *(us4*)&d[(size_t)i << 2] = o;
}

__global__ __launch_bounds__(256) void bias_copy(const float* bq, const float* bk,
                                                 const float* bv, const float* bo,
                                                 float* dst) {
  int i = blockIdx.x * 256 + threadIdx.x;   // grid 16 -> 4096
  int sel = i >> 10, idx = i & 1023;
  const float* p = sel == 0 ? bq : sel == 1 ? bk : sel == 2 ? bv : bo;
  dst[i] = p[idx];
}

// ---------------- 256x256 8-phase register-resident B^T GEMM ----------------
// C[m][n] = scale * sum_k A[m][k]*B[n][k] (+bias). A,B bf16 k-contiguous.
// 512 threads = 8 waves (2M x 4N); per-wave output 128x64 (2 halves each dim).
// EPI: 0 = QKV split (cols<2048 -> QK + bias; cols>=2048 -> Vt transposed + bias)
//      1 = bf16 out, scale      2 = f32 out, scale + bias

#define RD_A(dst, basep)                                                   \
  _Pragma("unroll") for (int mi = 0; mi < 4; ++mi)                         \
  _Pragma("unroll") for (int ks = 0; ks < 2; ++ks)                         \
      dst[mi][ks] = *(const short8*)((basep) + offA[mi][ks]);

#define RD_B(dst, basep)                                                   \
  _Pragma("unroll") for (int nj = 0; nj < 2; ++nj)                         \
  _Pragma("unroll") for (int ks = 0; ks < 2; ++ks)                         \
      dst[nj][ks] = *(const short8*)((basep) + offB[nj][ks]);

#define MFMA16(AF, BF, MI0, NJ0)                                           \
  __builtin_amdgcn_s_setprio(1);                                           \
  _Pragma("unroll") for (int ks = 0; ks < 2; ++ks)                         \
  _Pragma("unroll") for (int mi = 0; mi < 4; ++mi)                         \
  _Pragma("unroll") for (int nj = 0; nj < 2; ++nj)                         \
      acc[(MI0) + mi][(NJ0) + nj] = __builtin_amdgcn_mfma_f32_16x16x32_bf16( \
          AF[mi][ks], BF[nj][ks], acc[(MI0) + mi][(NJ0) + nj], 0, 0, 0);   \
  __builtin_amdgcn_s_setprio(0);

template<int EPI, bool CLAMP_K, bool SKIP_UPPER>
__global__ __launch_bounds__(512, 2)
void gemm8(const unsigned short* __restrict__ A, const unsigned short* __restrict__ B,
           void* __restrict__ Cout, unsigned short* __restrict__ Vt,
           const float* __restrict__ bias, float scale, int K,
           int lda, int ldb, int ldc,
           long long sAz, long long sBz, long long sCz)
{
  const int m0 = blockIdx.y << 8;
  const int n0 = blockIdx.x << 8;
  if (SKIP_UPPER && n0 > m0 + 255) return;   // fully-masked score block
  const int z = blockIdx.z;

  __shared__ unsigned short lA[2][2][8192];  // [dbuf][half: rows h*128..][128*64]
  __shared__ unsigned short lB[2][2][8192];

  const int tid = threadIdx.x, lane = tid & 63, wid = tid >> 6;
  const int wm = wid >> 2, wn = wid & 3;     // 2 x 4 waves
  const int fr = lane & 15, kg = lane >> 4;

  int kEnd = K;
  if (CLAMP_K) kEnd = (m0 + 256 < K) ? m0 + 256 : K;   // causal PV clamp
  const int nt = kEnd >> 6;

  const unsigned short* Ab = A + (size_t)z * sAz;
  const unsigned short* Bb = B + (size_t)z * sBz;

  // ds_read byte offsets within a 16KB half.
  // Swizzle: 16B slot index (0..7) XORed with (row&7) — FULL-slot XOR (no
  // additive carry: ks*64+kg*16 composed before the XOR).
  const int xorv = (fr & 7) << 4;
  int offA[4][2], offB[2][2];
#pragma unroll
  for (int mi = 0; mi < 4; ++mi)
#pragma unroll
    for (int ks = 0; ks < 2; ++ks)
      offA[mi][ks] = ((wm << 6) + (mi << 4) + fr) * 128 + (((ks << 6) + (kg << 4)) ^ xorv);
#pragma unroll
  for (int nj = 0; nj < 2; ++nj)
#pragma unroll
    for (int ks = 0; ks < 2; ++ks)
      offB[nj][ks] = ((wn << 5) + (nj << 4) + fr) * 128 + (((ks << 6) + (kg << 4)) ^ xorv);

  // staging: dest linear (row = tid>>3 (+64c), slot = tid&7);
  // source slot inverse-swizzled so swizzled reads see logical data
  const int srow = tid >> 3;
  const int scol = (((tid & 7) ^ (srow & 7)) << 3);   // elements (slot*16B)
  const unsigned short* aS = Ab + (size_t)(m0 + srow) * lda + scol;
  const unsigned short* bS = Bb + (size_t)(n0 + srow) * ldb + scol;

  auto stA = [&](int buf, int h, int tt) {
    int ttc = tt < nt ? tt : nt - 1;         // tail: harmless re-stage
    const unsigned short* s0 = aS + (size_t)(h << 7) * lda + (ttc << 6);
#pragma unroll
    for (int c = 0; c < 2; ++c)
      __builtin_amdgcn_global_load_lds(
          (const __attribute__((address_space(1))) void*)(s0 + (size_t)(c << 6) * lda),
          (__attribute__((address_space(3))) void*)((char*)&lA[buf][h][0] + (c << 13) + (tid << 4)),
          16, 0, 0);
  };
  auto stB = [&](int buf, int h, int tt) {
    int ttc = tt < nt ? tt : nt - 1;
    const unsigned short* s0 = bS + (size_t)(h << 7) * ldb + (ttc << 6);
#pragma unroll
    for (int c = 0; c < 2; ++c)
      __builtin_amdgcn_global_load_lds(
          (const __attribute__((address_space(1))) void*)(s0 + (size_t)(c << 6) * ldb),
          (__attribute__((address_space(3))) void*)((char*)&lB[buf][h][0] + (c << 13) + (tid << 4)),
          16, 0, 0);
  };

  f32x4 acc[8][4];
#pragma unroll
  for (int i = 0; i < 8; ++i)
#pragma unroll
    for (int j = 0; j < 4; ++j) acc[i][j] = f32x4{0.f, 0.f, 0.f, 0.f};

  // prologue: tile0 (8 ops) + B(1)h0, A(1)h1 (4 ops); vmcnt(4) -> tile0 landed
  stA(0, 0, 0); stB(0, 0, 0); stA(0, 1, 0); stB(0, 1, 0); stB(1, 0, 1); stA(1, 1, 1);
  asm volatile("s_waitcnt vmcnt(4)" ::: "memory");
  __builtin_amdgcn_s_barrier();

  for (int t = 0; t < nt; ++t) {
    const int buf = t & 1;
    const char* Ab0 = (const char*)&lA[buf][0][0];
    const char* Ab1 = (const char*)&lA[buf][1][0];
    const char* Bb0 = (const char*)&lB[buf][0][0];
    const char* Bb1 = (const char*)&lB[buf][1][0];

    short8 a0[4][2], a1[4][2], b0[2][2], b1[2][2];

    // q0: read a0(8) + b0(4); stage B(t+1)h1; MFMA quad (0,0)
    RD_A(a0, Ab0);
    RD_B(b0, Bb0);
    stB((t + 1) & 1, 1, t + 1);
    asm volatile("s_waitcnt lgkmcnt(8)" ::: "memory");
    __builtin_amdgcn_s_barrier();
    asm volatile("s_waitcnt lgkmcnt(0)" ::: "memory");
    __builtin_amdgcn_sched_barrier(0);
    MFMA16(a0, b0, 0, 0);
    __builtin_amdgcn_s_barrier();

    // q1: read a1(8); stage A(t+1)h0; MFMA quad (1,0)  (reuse b0)
    RD_A(a1, Ab1);
    stA((t + 1) & 1, 0, t + 1);
    __builtin_amdgcn_s_barrier();
    asm volatile("s_waitcnt lgkmcnt(0)" ::: "memory");
    __builtin_amdgcn_sched_barrier(0);
    MFMA16(a1, b0, 4, 0);
    __builtin_amdgcn_s_barrier();

    // q2: read b1(4); stage B(t+2)h0 (lB[buf][0] last read at q0); MFMA (1,1)
    RD_B(b1, Bb1);
    stB(buf, 0, t + 2);
    __builtin_amdgcn_s_barrier();
    asm volatile("s_waitcnt lgkmcnt(0)" ::: "memory");
    __builtin_amdgcn_sched_barrier(0);
    MFMA16(a1, b1, 4, 2);
    __builtin_amdgcn_s_barrier();

    // q3: stage A(t+2)h1 (lA[buf][1] last read at q1); vmcnt(4): tile t+1
    // fully landed (only q2/q3 stages still in flight); MFMA (0,1) (a0,b1)
    stA(buf, 1, t + 2);
    asm volatile("s_waitcnt vmcnt(4)" ::: "memory");
    __builtin_amdgcn_s_barrier();
    MFMA16(a0, b1, 0, 2);
    __builtin_amdgcn_s_barrier();
  }
  asm volatile("s_waitcnt vmcnt(0)" ::: "memory");  // drain stray LDS writes

  // epilogue: C frag layout col=lane&15, row=(lane>>4)*4+reg
#pragma unroll
  for (int mig = 0; mig < 8; ++mig)
#pragma unroll
    for (int njg = 0; njg < 4; ++njg) {
      const int row = m0 + (mig >> 2) * 128 + wm * 64 + (mig & 3) * 16 + (kg << 2);
      const int col = n0 + (njg >> 1) * 128 + wn * 32 + (njg & 1) * 16 + fr;
      f32x4 v = acc[mig][njg];
      if (EPI == 0) {
        const float bb = bias[col];
        if (col < 2048) {
          unsigned short* Ch = (unsigned short*)Cout;
#pragma unroll
          for (int jj = 0; jj < 4; ++jj)
            Ch[(size_t)(row + jj) * 2048 + col] = f2b(v[jj] + bb);
        } else {
          const int batch = row >> 11, t0 = row & 2047, cc = col - 2048;
          us4 o;
#pragma unroll
          for (int jj = 0; jj < 4; ++jj) o[jj] = f2b(v[jj] + bb);
          *(us4*)&Vt[(size_t)batch * (1024 * 2048) + (size_t)cc * 2048 + t0] = o;
        }
      } else if (EPI == 1) {
        unsigned short* Ch = (unsigned short*)Cout + (size_t)z * sCz;
#pragma unroll
        for (int jj = 0; jj < 4; ++jj)
          Ch[(size_t)(row + jj) * ldc + col] = f2b(v[jj] * scale);
      } else {
        float* Cf = (float*)Cout + (size_t)z * sCz;
        const float bb = bias[col];
#pragma unroll
        for (int jj = 0; jj < 4; ++jj)
          Cf[(size_t)(row + jj) * ldc + col] = v[jj] * scale + bb;
      }
    }
}

// ---------------- causal softmax, in-place over bf16 rows ----------------
__global__ __launch_bounds__(256)
void softmax_causal(unsigned short* __restrict__ S, int T) {
  const int t = blockIdx.x, b = blockIdx.y;
  unsigned short* row = S + ((size_t)b * T + t) * T;
  const int tid  = threadIdx.x;
  const int lane = tid & 63;
  const int wid  = tid >> 6;
  const int base = tid << 3;   // 256 threads * 8 = 2048

  us8 raw = *(const us8*)&row[base];
  float v[8];
  float mx = -3.0e38f;
#pragma unroll
  for (int j = 0; j < 8; ++j) {
    const int s = base + j;
    v[j] = (s <= t) ? b2f(raw[j]) : -3.0e38f;
    mx = fmaxf(mx, v[j]);
  }
#pragma unroll
  for (int m = 32; m; m >>= 1) mx = fmaxf(mx, __shfl_xor(mx, m, 64));
  __shared__ float red[4];
  if (lane == 0) red[wid] = mx;
  __syncthreads();
  mx = fmaxf(fmaxf(red[0], red[1]), fmaxf(red[2], red[3]));

  float e[8];
  float sum = 0.f;
#pragma unroll
  for (int j = 0; j < 8; ++j) { e[j] = __expf(v[j] - mx); sum += e[j]; }
#pragma unroll
  for (int m = 32; m; m >>= 1) sum += __shfl_xor(sum, m, 64);
  __syncthreads();
  if (lane == 0) red[wid] = sum;
  __syncthreads();
  sum = red[0] + red[1] + red[2] + red[3];
  const float inv = 1.f / sum;

  us8 o;
#pragma unroll
  for (int j = 0; j < 8; ++j) o[j] = f2b(e[j] * inv);
  *(us8*)&row[base] = o;
}

// ---------------- host-side launch ----------------
extern "C" void kernel_launch(void* const* d_in, const int* in_sizes, int n_in,
                              void* d_out, int out_size, void* d_ws, size_t ws_size,
                              hipStream_t stream) {
  (void)in_sizes; (void)n_in; (void)out_size; (void)ws_size;
  const float* x  = (const float*)d_in[0];
  const float* Wq = (const float*)d_in[1];
  const float* bq = (const float*)d_in[2];
  const float* Wk = (const float*)d_in[3];
  const float* bk = (const float*)d_in[4];
  const float* Wv = (const float*)d_in[5];
  const float* bv = (const float*)d_in[6];
  const float* Wo = (const float*)d_in[7];
  const float* bo = (const float*)d_in[8];

  const int B = 4, T = 2048, C = 1024;
  const int M = B * T;                                   // 8192

  unsigned short* xb    = (unsigned short*)d_ws;         // M*C (reused as attn)
  unsigned short* Wqkvb = xb    + (size_t)M * C;         // 3C*C packed [Wq|Wk|Wv]
  unsigned short* Wob   = Wqkvb + (size_t)3 * C * C;     // C*C
  unsigned short* QK    = Wob   + (size_t)C * C;         // M*2C  [Q|K]
  unsigned short* VtB   = QK    + (size_t)M * 2 * C;     // B*C*T  [b][c][t]
  unsigned short* S     = VtB   + (size_t)M * C;         // B*T*T (becomes P)
  float*          bws   = (float*)(S + (size_t)B * T * T); // 4096: bq|bk|bv|bo
  unsigned short* attn  = xb;

  // 1. converts + packing
  cvt_kernel<<<M * C / 4 / 256, 256, 0, stream>>>(x, xb, M * C / 4);
  cvt4_kernel<<<dim3(C * C / 4 / 256, 4), 256, 0, stream>>>(
      Wq, Wk, Wv, Wo,
      Wqkvb, Wqkvb + (size_t)C * C, Wqkvb + (size_t)2 * C * C, Wob, C * C / 4);
  bias_copy<<<16, 256, 0, stream>>>(bq, bk, bv, bo, bws);

  // 2. fused QKV projection: [Q|K] -> QK, V -> Vt (transposed)
  gemm8<0, false, false><<<dim3(3 * C / 256, M / 256, 1), 512, 0, stream>>>(
      xb, Wqkvb, QK, VtB, bws, 1.f, C, C, C, 0, 0LL, 0LL, 0LL);

  // 3. scores: S = Q K^T / 32 (bf16), lower-triangle 256-blocks only
  gemm8<1, false, true><<<dim3(T / 256, T / 256, B), 512, 0, stream>>>(
      QK, QK + C, S, nullptr, nullptr, 0.03125f, C, 2 * C, 2 * C, T,
      (long long)T * 2 * C, (long long)T * 2 * C, (long long)T * T);

  // 4. causal softmax in-place (writes zeros above diagonal)
  softmax_causal<<<dim3(T, B), 256, 0, stream>>>(S, T);

  // 5. attn = P @ V (B-operand Vt[b][c][s], K causally clamped)
  gemm8<1, true, false><<<dim3(C / 256, T / 256, B), 512, 0, stream>>>(
      S, VtB, attn, nullptr, nullptr, 1.f, T, T, T, C,
      (long long)T * T, (long long)C * T, (long long)T * C);

  // 6. out = attn Wo^T + bo (fp32)
  gemm8<2, false, false><<<dim3(C / 256, M / 256, 1), 512, 0, stream>>>(
      attn, Wob, d_out, nullptr, bws + 3 * C, 1.f, C, C, C, C, 0LL, 0LL, 0LL);
}

// Round 5
// 218.536 us; speedup vs baseline: 1.4481x; 1.0010x over previous
//
#include <hip/hip_runtime.h>

// Masked self-attention, B=4 T=2048 C=1024 (single head, head dim = C).
// All GEMMs: 256x256 / BK=64 / 8-wave register-resident 8-phase bf16 MFMA
// (m201 template). Fragments read ONCE per K-tile (12+8+4+0 ds_read_b128),
// quadrants reuse registers. LDS swizzle: 16B-slot ^= (row&7), both-sides.
// One counted vmcnt(4) per K-tile; NO forced lgkm drains (compiler handles
// ds_read->MFMA deps with fine-grained lgkmcnt).
// Pipeline:
//   QK-proj (256 blk, 1 round) -> QK[8192][2048] = [Q|K], bias col
//   Vt-proj = Wv @ x^T (row-major Vt[1024][8192], bias row) - no scatter
//   scores  = Q K^T /32 (bf16, lower-tri blocks), softmax in-place
//   PV      = P @ V (B = Vt, ldb 8192, z-off 2048; causal K-clamp)
//   out     = attn Wo^T + bo (f32)

typedef __attribute__((ext_vector_type(8))) short short8;
typedef __attribute__((ext_vector_type(4))) float f32x4;
typedef __attribute__((ext_vector_type(4))) unsigned short us4;
typedef __attribute__((ext_vector_type(8))) unsigned short us8;
typedef __attribute__((ext_vector_type(4))) float fl4;

__device__ __forceinline__ unsigned short f2b(float f) {
  unsigned int u = __builtin_bit_cast(unsigned int, f);
  u += 0x7fffu + ((u >> 16) & 1u);   // round-to-nearest-even
  return (unsigned short)(u >> 16);
}
__device__ __forceinline__ float b2f(unsigned short h) {
  unsigned int u = ((unsigned int)h) << 16;
  return __builtin_bit_cast(float, u);
}

// ---------------- fp32 -> bf16 converts ----------------
__global__ __launch_bounds__(256) void cvt_kernel(const float* __restrict__ src,
                                                  unsigned short* __restrict__ dst,
                                                  int n4) {
  int i = blockIdx.x * blockDim.x + threadIdx.x;
  if (i < n4) {
    fl4 f = *(const fl4*)&src[(size_t)i << 2];
    us4 o;
#pragma unroll
    for (int j = 0; j < 4; ++j) o[j] = f2b(f[j]);
    *(us4*)&dst[(size_t)i << 2] = o;
  }
}

__global__ __launch_bounds__(256) void cvt4_kernel(
    const float* s0, const float* s1, const float* s2, const float* s3,
    unsigned short* d0, unsigned short* d1, unsigned short* d2, unsigned short* d3,
    int n4) {
  int i = blockIdx.x * 256 + threadIdx.x;
  if (i >= n4) return;
  int w = blockIdx.y;
  const float* s = w == 0 ? s0 : w == 1 ? s1 : w == 2 ? s2 : s3;
  unsigned short* d = w == 0 ? d0 : w == 1 ? d1 : w == 2 ? d2 : d3;
  fl4 f = *(const fl4*)&s[(size_t)i << 2];
  us4 o;
#pragma unroll
  for (int j = 0; j < 4; ++j) o[j] = f2b(f[j]);
  *(us4*)&d[(size_t)i << 2] = o;
}

__global__ __launch_bounds__(256) void bias_copy(const float* bq, const float* bk,
                                                 const float* bv, const float* bo,
                                                 float* dst) {
  int i = blockIdx.x * 256 + threadIdx.x;   // grid 16 -> 4096
  int sel = i >> 10, idx = i & 1023;
  const float* p = sel == 0 ? bq : sel == 1 ? bk : sel == 2 ? bv : bo;
  dst[i] = p[idx];
}

// ---------------- 256x256 8-phase register-resident B^T GEMM ----------------
// C[m][n] = scale * sum_k A[m][k]*B[n][k] (+bias). A,B bf16 k-contiguous.
// 512 threads = 8 waves (2M x 4N); per-wave output 128x64.
// EPI: 1 = bf16, *scale            2 = f32, *scale + bias[col]
//      3 = bf16, + bias[col]       4 = bf16, + bias[row]

#define RD_A(dst, basep)                                                   \
  _Pragma("unroll") for (int mi = 0; mi < 4; ++mi)                         \
  _Pragma("unroll") for (int ks = 0; ks < 2; ++ks)                         \
      dst[mi][ks] = *(const short8*)((basep) + offA[mi][ks]);

#define RD_B(dst, basep)                                                   \
  _Pragma("unroll") for (int nj = 0; nj < 2; ++nj)                         \
  _Pragma("unroll") for (int ks = 0; ks < 2; ++ks)                         \
      dst[nj][ks] = *(const short8*)((basep) + offB[nj][ks]);

#define MFMA16(AF, BF, MI0, NJ0)                                           \
  __builtin_amdgcn_s_setprio(1);                                           \
  _Pragma("unroll") for (int ks = 0; ks < 2; ++ks)                         \
  _Pragma("unroll") for (int mi = 0; mi < 4; ++mi)                         \
  _Pragma("unroll") for (int nj = 0; nj < 2; ++nj)                         \
      acc[(MI0) + mi][(NJ0) + nj] = __builtin_amdgcn_mfma_f32_16x16x32_bf16( \
          AF[mi][ks], BF[nj][ks], acc[(MI0) + mi][(NJ0) + nj], 0, 0, 0);   \
  __builtin_amdgcn_s_setprio(0);

template<int EPI, bool CLAMP_K, bool SKIP_UPPER>
__global__ __launch_bounds__(512, 2)
void gemm8(const unsigned short* __restrict__ A, const unsigned short* __restrict__ B,
           void* __restrict__ Cout, const float* __restrict__ bias,
           float scale, int K, int lda, int ldb, int ldc,
           long long sAz, long long sBz, long long sCz)
{
  const int m0 = blockIdx.y << 8;
  const int n0 = blockIdx.x << 8;
  if (SKIP_UPPER && n0 > m0 + 255) return;   // fully-masked score block
  const int z = blockIdx.z;

  __shared__ unsigned short lA[2][2][8192];  // [dbuf][half: rows h*128..][128*64]
  __shared__ unsigned short lB[2][2][8192];

  const int tid = threadIdx.x, lane = tid & 63, wid = tid >> 6;
  const int wm = wid >> 2, wn = wid & 3;     // 2 x 4 waves
  const int fr = lane & 15, kg = lane >> 4;

  int kEnd = K;
  if (CLAMP_K) kEnd = (m0 + 256 < K) ? m0 + 256 : K;   // causal PV clamp
  const int nt = kEnd >> 6;

  const unsigned short* Ab = A + (size_t)z * sAz;
  const unsigned short* Bb = B + (size_t)z * sBz;

  // ds_read byte offsets within a 16KB half; 16B-slot index XORed with row&7
  const int xorv = (fr & 7) << 4;
  int offA[4][2], offB[2][2];
#pragma unroll
  for (int mi = 0; mi < 4; ++mi)
#pragma unroll
    for (int ks = 0; ks < 2; ++ks)
      offA[mi][ks] = ((wm << 6) + (mi << 4) + fr) * 128 + (((ks << 6) + (kg << 4)) ^ xorv);
#pragma unroll
  for (int nj = 0; nj < 2; ++nj)
#pragma unroll
    for (int ks = 0; ks < 2; ++ks)
      offB[nj][ks] = ((wn << 5) + (nj << 4) + fr) * 128 + (((ks << 6) + (kg << 4)) ^ xorv);

  // staging: dest linear (row = tid>>3 (+64c), slot = tid&7);
  // source slot inverse-swizzled so swizzled reads see logical data
  const int srow = tid >> 3;
  const int scol = (((tid & 7) ^ (srow & 7)) << 3);   // elements (slot*16B)
  const unsigned short* aS = Ab + (size_t)(m0 + srow) * lda + scol;
  const unsigned short* bS = Bb + (size_t)(n0 + srow) * ldb + scol;

  auto stA = [&](int buf, int h, int tt) {
    int ttc = tt < nt ? tt : nt - 1;         // tail: harmless dummy re-stage
    const unsigned short* s0 = aS + (size_t)(h << 7) * lda + (ttc << 6);
#pragma unroll
    for (int c = 0; c < 2; ++c)
      __builtin_amdgcn_global_load_lds(
          (const __attribute__((address_space(1))) void*)(s0 + (size_t)(c << 6) * lda),
          (__attribute__((address_space(3))) void*)((char*)&lA[buf][h][0] + (c << 13) + (tid << 4)),
          16, 0, 0);
  };
  auto stB = [&](int buf, int h, int tt) {
    int ttc = tt < nt ? tt : nt - 1;
    const unsigned short* s0 = bS + (size_t)(h << 7) * ldb + (ttc << 6);
#pragma unroll
    for (int c = 0; c < 2; ++c)
      __builtin_amdgcn_global_load_lds(
          (const __attribute__((address_space(1))) void*)(s0 + (size_t)(c << 6) * ldb),
          (__attribute__((address_space(3))) void*)((char*)&lB[buf][h][0] + (c << 13) + (tid << 4)),
          16, 0, 0);
  };

  f32x4 acc[8][4];
#pragma unroll
  for (int i = 0; i < 8; ++i)
#pragma unroll
    for (int j = 0; j < 4; ++j) acc[i][j] = f32x4{0.f, 0.f, 0.f, 0.f};

  // prologue: tile0 (8 ops) + B(1)h0, A(1)h1; vmcnt(4) -> tile0 landed
  stA(0, 0, 0); stB(0, 0, 0); stA(0, 1, 0); stB(0, 1, 0); stB(1, 0, 1); stA(1, 1, 1);
  asm volatile("s_waitcnt vmcnt(4)" ::: "memory");
  __builtin_amdgcn_s_barrier();

  for (int t = 0; t < nt; ++t) {
    const int buf = t & 1;
    const char* Ab0 = (const char*)&lA[buf][0][0];
    const char* Ab1 = (const char*)&lA[buf][1][0];
    const char* Bb0 = (const char*)&lB[buf][0][0];
    const char* Bb1 = (const char*)&lB[buf][1][0];

    short8 a0[4][2], a1[4][2], b0[2][2], b1[2][2];

    // q0: read a0(8)+b0(4); stage B(t+1)h1; MFMA quad (0,0)
    RD_A(a0, Ab0);
    RD_B(b0, Bb0);
    stB((t + 1) & 1, 1, t + 1);
    __builtin_amdgcn_s_barrier();
    MFMA16(a0, b0, 0, 0);
    __builtin_amdgcn_s_barrier();

    // q1: read a1(8); stage A(t+1)h0; MFMA quad (1,0)  (reuse b0)
    RD_A(a1, Ab1);
    stA((t + 1) & 1, 0, t + 1);
    __builtin_amdgcn_s_barrier();
    MFMA16(a1, b0, 4, 0);
    __builtin_amdgcn_s_barrier();

    // q2: read b1(4); stage B(t+2)h0 (last read of lB[buf][0] was q0); MFMA (1,1)
    RD_B(b1, Bb1);
    stB(buf, 0, t + 2);
    __builtin_amdgcn_s_barrier();
    MFMA16(a1, b1, 4, 2);
    __builtin_amdgcn_s_barrier();

    // q3: stage A(t+2)h1 (last read of lA[buf][1] was q1); vmcnt(4) = tile t+1
    // fully landed (only q2/q3 stages in flight); MFMA (0,1) (reuse a0,b1)
    stA(buf, 1, t + 2);
    asm volatile("s_waitcnt vmcnt(4)" ::: "memory");
    __builtin_amdgcn_s_barrier();
    MFMA16(a0, b1, 0, 2);
    __builtin_amdgcn_s_barrier();
  }
  asm volatile("s_waitcnt vmcnt(0)" ::: "memory");  // drain dummy tail stages

  // epilogue: C frag layout col=lane&15, row=(lane>>4)*4+reg
#pragma unroll
  for (int mig = 0; mig < 8; ++mig)
#pragma unroll
    for (int njg = 0; njg < 4; ++njg) {
      const int row = m0 + (mig >> 2) * 128 + wm * 64 + (mig & 3) * 16 + (kg << 2);
      const int col = n0 + (njg >> 1) * 128 + wn * 32 + (njg & 1) * 16 + fr;
      f32x4 v = acc[mig][njg];
      if (EPI == 1) {
        unsigned short* Ch = (unsigned short*)Cout + (size_t)z * sCz;
#pragma unroll
        for (int jj = 0; jj < 4; ++jj)
          Ch[(size_t)(row + jj) * ldc + col] = f2b(v[jj] * scale);
      } else if (EPI == 2) {
        float* Cf = (float*)Cout + (size_t)z * sCz;
        const float bb = bias[col];
#pragma unroll
        for (int jj = 0; jj < 4; ++jj)
          Cf[(size_t)(row + jj) * ldc + col] = v[jj] * scale + bb;
      } else if (EPI == 3) {
        unsigned short* Ch = (unsigned short*)Cout;
        const float bb = bias[col];
#pragma unroll
        for (int jj = 0; jj < 4; ++jj)
          Ch[(size_t)(row + jj) * ldc + col] = f2b(v[jj] + bb);
      } else {   // EPI == 4: bias by row (Vt-proj: row = output channel c)
        unsigned short* Ch = (unsigned short*)Cout;
#pragma unroll
        for (int jj = 0; jj < 4; ++jj)
          Ch[(size_t)(row + jj) * ldc + col] = f2b(v[jj] + bias[row + jj]);
      }
    }
}

// ---------------- causal softmax, in-place over bf16 rows ----------------
__global__ __launch_bounds__(256)
void softmax_causal(unsigned short* __restrict__ S, int T) {
  const int t = blockIdx.x, b = blockIdx.y;
  unsigned short* row = S + ((size_t)b * T + t) * T;
  const int tid  = threadIdx.x;
  const int lane = tid & 63;
  const int wid  = tid >> 6;
  const int base = tid << 3;   // 256 threads * 8 = 2048

  us8 raw = *(const us8*)&row[base];
  float v[8];
  float mx = -3.0e38f;
#pragma unroll
  for (int j = 0; j < 8; ++j) {
    const int s = base + j;
    v[j] = (s <= t) ? b2f(raw[j]) : -3.0e38f;
    mx = fmaxf(mx, v[j]);
  }
#pragma unroll
  for (int m = 32; m; m >>= 1) mx = fmaxf(mx, __shfl_xor(mx, m, 64));
  __shared__ float red[4];
  if (lane == 0) red[wid] = mx;
  __syncthreads();
  mx = fmaxf(fmaxf(red[0], red[1]), fmaxf(red[2], red[3]));

  float e[8];
  float sum = 0.f;
#pragma unroll
  for (int j = 0; j < 8; ++j) { e[j] = __expf(v[j] - mx); sum += e[j]; }
#pragma unroll
  for (int m = 32; m; m >>= 1) sum += __shfl_xor(sum, m, 64);
  __syncthreads();
  if (lane == 0) red[wid] = sum;
  __syncthreads();
  sum = red[0] + red[1] + red[2] + red[3];
  const float inv = 1.f / sum;

  us8 o;
#pragma unroll
  for (int j = 0; j < 8; ++j) o[j] = f2b(e[j] * inv);
  *(us8*)&row[base] = o;
}

// ---------------- host-side launch ----------------
extern "C" void kernel_launch(void* const* d_in, const int* in_sizes, int n_in,
                              void* d_out, int out_size, void* d_ws, size_t ws_size,
                              hipStream_t stream) {
  (void)in_sizes; (void)n_in; (void)out_size; (void)ws_size;
  const float* x  = (const float*)d_in[0];
  const float* Wq = (const float*)d_in[1];
  const float* bq = (const float*)d_in[2];
  const float* Wk = (const float*)d_in[3];
  const float* bk = (const float*)d_in[4];
  const float* Wv = (const float*)d_in[5];
  const float* bv = (const float*)d_in[6];
  const float* Wo = (const float*)d_in[7];
  const float* bo = (const float*)d_in[8];

  const int B = 4, T = 2048, C = 1024;
  const int M = B * T;                                   // 8192

  unsigned short* xb    = (unsigned short*)d_ws;         // M*C (reused as attn)
  unsigned short* Wqkvb = xb    + (size_t)M * C;         // [Wq|Wk|Wv] packed
  unsigned short* Wob   = Wqkvb + (size_t)3 * C * C;     // C*C
  unsigned short* QK    = Wob   + (size_t)C * C;         // M*2C  [Q|K]
  unsigned short* Vt    = QK    + (size_t)M * 2 * C;     // [1024][8192] row-major
  unsigned short* S     = Vt    + (size_t)M * C;         // B*T*T (becomes P)
  float*          bws   = (float*)(S + (size_t)B * T * T); // 4096: bq|bk|bv|bo
  unsigned short* attn  = xb;

  // 1. converts + packing
  cvt_kernel<<<M * C / 4 / 256, 256, 0, stream>>>(x, xb, M * C / 4);
  cvt4_kernel<<<dim3(C * C / 4 / 256, 4), 256, 0, stream>>>(
      Wq, Wk, Wv, Wo,
      Wqkvb, Wqkvb + (size_t)C * C, Wqkvb + (size_t)2 * C * C, Wob, C * C / 4);
  bias_copy<<<16, 256, 0, stream>>>(bq, bk, bv, bo, bws);

  // 2a. QK projection: QK[t][0:2048] = x @ [Wq|Wk]^T + [bq|bk]  (256 blocks)
  gemm8<3, false, false><<<dim3(2 * C / 256, M / 256, 1), 512, 0, stream>>>(
      xb, Wqkvb, QK, bws, 1.f, C, C, C, 2 * C, 0LL, 0LL, 0LL);

  // 2b. Vt = Wv @ x^T + bv[row]: Vt[c][t_glob], row-major coalesced
  gemm8<4, false, false><<<dim3(M / 256, C / 256, 1), 512, 0, stream>>>(
      Wqkvb + (size_t)2 * C * C, xb, Vt, bws + 2 * C, 1.f, C, C, C, M,
      0LL, 0LL, 0LL);

  // 3. scores: S = Q K^T / 32 (bf16), lower-triangle 256-blocks only
  gemm8<1, false, true><<<dim3(T / 256, T / 256, B), 512, 0, stream>>>(
      QK, QK + C, S, nullptr, 0.03125f, C, 2 * C, 2 * C, T,
      (long long)T * 2 * C, (long long)T * 2 * C, (long long)T * T);

  // 4. causal softmax in-place (writes zeros above diagonal)
  softmax_causal<<<dim3(T, B), 256, 0, stream>>>(S, T);

  // 5. attn = P @ V: B[n=c][k=s] = Vt[c][b*2048+s] (ldb=8192, z-off 2048)
  gemm8<1, true, false><<<dim3(C / 256, T / 256, B), 512, 0, stream>>>(
      S, Vt, attn, nullptr, 1.f, T, T, M, C,
      (long long)T * T, 2048LL, (long long)T * C);

  // 6. out = attn Wo^T + bo (fp32)
  gemm8<2, false, false><<<dim3(C / 256, M / 256, 1), 512, 0, stream>>>(
      attn, Wob, d_out, bws + 3 * C, 1.f, C, C, C, C, 0LL, 0LL, 0LL);
}

// Round 6
// 206.932 us; speedup vs baseline: 1.5293x; 1.0561x over previous
//
#include <hip/hip_runtime.h>

// Masked self-attention, B=4 T=2048 C=1024 (single head, head dim = C).
// All GEMMs: 256x256 / BK=64 / 8-wave register-resident 8-phase bf16 MFMA
// (m201 template): fragments read ONCE per K-tile (12+8+4+0 ds_read_b128),
// quadrants reuse registers; 16B-slot LDS swizzle both-sides; one counted
// vmcnt(4) per K-tile; setprio around MFMA; T1 XCD-bijective block swizzle.
// Pipeline:
//   prep    : x->bf16, 4 weights->bf16 packed, biases packed   (1 launch)
//   QK-proj : QK[8192][2048] = x @ [Wq|Wk]^T + [bq|bk]
//   Vt-proj : Vt[1024][8192] = Wv @ x^T + bv[row]  (row-major, coalesced)
//   scores  : S = Q K^T / 32 (bf16, lower-tri 256-blocks only)
//   softmax : in-place causal, zeros above diagonal
//   PV      : split-K=2 (balanced causal clamp) -> bf16 partials P0|P1
//             (overlaid on dead QK region)
//   reduce  : attn = P0 + P1   (into dead xb region)
//   out     : out = attn Wo^T + bo (f32)

typedef __attribute__((ext_vector_type(8))) short short8;
typedef __attribute__((ext_vector_type(4))) float f32x4;
typedef __attribute__((ext_vector_type(4))) unsigned short us4;
typedef __attribute__((ext_vector_type(8))) unsigned short us8;
typedef __attribute__((ext_vector_type(4))) float fl4;

__device__ __forceinline__ unsigned short f2b(float f) {
  unsigned int u = __builtin_bit_cast(unsigned int, f);
  u += 0x7fffu + ((u >> 16) & 1u);   // round-to-nearest-even
  return (unsigned short)(u >> 16);
}
__device__ __forceinline__ float b2f(unsigned short h) {
  unsigned int u = ((unsigned int)h) << 16;
  return __builtin_bit_cast(float, u);
}

// ---------------- merged prep: converts + bias packing ----------------
// blocks [0,8192): x -> xb ; [8192,12288): weights ; [12288,12304): biases
__global__ __launch_bounds__(256) void prep_kernel(
    const float* __restrict__ x,
    const float* __restrict__ Wq, const float* __restrict__ Wk,
    const float* __restrict__ Wv, const float* __restrict__ Wo,
    const float* __restrict__ bq, const float* __restrict__ bk,
    const float* __restrict__ bv, const float* __restrict__ bo,
    unsigned short* __restrict__ xb, unsigned short* __restrict__ Wqkvb,
    unsigned short* __restrict__ Wob, float* __restrict__ bws) {
  const int bid = blockIdx.x;
  if (bid < 8192) {
    const int i = bid * 256 + threadIdx.x;          // 2M fl4 groups
    fl4 f = *(const fl4*)&x[(size_t)i << 2];
    us4 o;
#pragma unroll
    for (int j = 0; j < 4; ++j) o[j] = f2b(f[j]);
    *(us4*)&xb[(size_t)i << 2] = o;
  } else if (bid < 12288) {
    const int w = (bid - 8192) >> 10;
    const int i = ((bid - 8192) & 1023) * 256 + threadIdx.x;   // 256K fl4
    const float* s = w == 0 ? Wq : w == 1 ? Wk : w == 2 ? Wv : Wo;
    unsigned short* d = w < 3 ? Wqkvb + (size_t)w * 1024 * 1024 : Wob;
    fl4 f = *(const fl4*)&s[(size_t)i << 2];
    us4 o;
#pragma unroll
    for (int j = 0; j < 4; ++j) o[j] = f2b(f[j]);
    *(us4*)&d[(size_t)i << 2] = o;
  } else {
    const int i = (bid - 12288) * 256 + threadIdx.x;   // 4096
    const int sel = i >> 10, idx = i & 1023;
    const float* p = sel == 0 ? bq : sel == 1 ? bk : sel == 2 ? bv : bo;
    bws[i] = p[idx];
  }
}

// ---------------- 256x256 8-phase register-resident B^T GEMM ----------------
// C[m][n] = scale * sum_k A[m][k]*B[n][k] (+bias). A,B bf16 k-contiguous.
// 512 threads = 8 waves (2M x 4N); per-wave output 128x64.
// EPI: 1 = bf16 *scale (+z*sCz)    2 = f32 *scale + bias[col]
//      3 = bf16 + bias[col]        4 = bf16 + bias[row]
//      5 = bf16 split-K partial (half -> P0|P1, +zb*sCz)

#define RD_A(dst, basep)                                                   \
  _Pragma("unroll") for (int mi = 0; mi < 4; ++mi)                         \
  _Pragma("unroll") for (int ks = 0; ks < 2; ++ks)                         \
      dst[mi][ks] = *(const short8*)((basep) + offA[mi][ks]);

#define RD_B(dst, basep)                                                   \
  _Pragma("unroll") for (int nj = 0; nj < 2; ++nj)                         \
  _Pragma("unroll") for (int ks = 0; ks < 2; ++ks)                         \
      dst[nj][ks] = *(const short8*)((basep) + offB[nj][ks]);

#define MFMA16(AF, BF, MI0, NJ0)                                           \
  __builtin_amdgcn_s_setprio(1);                                           \
  _Pragma("unroll") for (int ks = 0; ks < 2; ++ks)                         \
  _Pragma("unroll") for (int mi = 0; mi < 4; ++mi)                         \
  _Pragma("unroll") for (int nj = 0; nj < 2; ++nj)                         \
      acc[(MI0) + mi][(NJ0) + nj] = __builtin_amdgcn_mfma_f32_16x16x32_bf16( \
          AF[mi][ks], BF[nj][ks], acc[(MI0) + mi][(NJ0) + nj], 0, 0, 0);   \
  __builtin_amdgcn_s_setprio(0);

template<int EPI, bool SPLIT, bool SKIP_UPPER>
__global__ __launch_bounds__(512, 2)
void gemm8(const unsigned short* __restrict__ A, const unsigned short* __restrict__ B,
           void* __restrict__ Cout, const float* __restrict__ bias,
           float scale, int K, int lda, int ldb, int ldc,
           long long sAz, long long sBz, long long sCz)
{
  // T1: XCD-bijective block swizzle (all grids have nwg % 8 == 0)
  const int gx = gridDim.x;
  const int nwg = gx * gridDim.y;
  int flat = blockIdx.y * gx + blockIdx.x;
  { const int q = nwg >> 3, r = nwg & 7, xc = flat & 7, i = flat >> 3;
    flat = (xc < r ? xc * (q + 1) : r * (q + 1) + (xc - r) * q) + i; }
  const int m0 = (flat / gx) << 8;
  const int n0 = (flat % gx) << 8;
  if (SKIP_UPPER && n0 > m0 + 255) return;   // fully-masked score block
  const int zraw = blockIdx.z;
  const int z = SPLIT ? (zraw >> 1) : zraw;

  int kBeg = 0, kEnd = K;
  if (SPLIT) {                      // balanced causal split (PV)
    const int kFull = m0 + 256;     // <= K(=2048) always here
    const int kMid = kFull >> 1;    // multiple of 128
    kBeg = (zraw & 1) ? kMid : 0;
    kEnd = (zraw & 1) ? kFull : kMid;
  }
  const int nt = (kEnd - kBeg) >> 6;

  __shared__ unsigned short lA[2][2][8192];  // [dbuf][half: rows h*128..][128*64]
  __shared__ unsigned short lB[2][2][8192];

  const int tid = threadIdx.x, lane = tid & 63, wid = tid >> 6;
  const int wm = wid >> 2, wn = wid & 3;     // 2 x 4 waves
  const int fr = lane & 15, kg = lane >> 4;

  const unsigned short* Ab = A + (size_t)z * sAz;
  const unsigned short* Bb = B + (size_t)z * sBz;

  // ds_read byte offsets within a 16KB half; 16B-slot index XORed with row&7
  const int xorv = (fr & 7) << 4;
  int offA[4][2], offB[2][2];
#pragma unroll
  for (int mi = 0; mi < 4; ++mi)
#pragma unroll
    for (int ks = 0; ks < 2; ++ks)
      offA[mi][ks] = ((wm << 6) + (mi << 4) + fr) * 128 + (((ks << 6) + (kg << 4)) ^ xorv);
#pragma unroll
  for (int nj = 0; nj < 2; ++nj)
#pragma unroll
    for (int ks = 0; ks < 2; ++ks)
      offB[nj][ks] = ((wn << 5) + (nj << 4) + fr) * 128 + (((ks << 6) + (kg << 4)) ^ xorv);

  // staging: dest linear (row = tid>>3 (+64c), slot = tid&7);
  // source slot inverse-swizzled so swizzled reads see logical data
  const int srow = tid >> 3;
  const int scol = (((tid & 7) ^ (srow & 7)) << 3);   // elements (slot*16B)
  const unsigned short* aS = Ab + (size_t)(m0 + srow) * lda + scol + kBeg;
  const unsigned short* bS = Bb + (size_t)(n0 + srow) * ldb + scol + kBeg;

  auto stA = [&](int buf, int h, int tt) {
    int ttc = tt < nt ? tt : nt - 1;         // tail: harmless dummy re-stage
    const unsigned short* s0 = aS + (size_t)(h << 7) * lda + (ttc << 6);
#pragma unroll
    for (int c = 0; c < 2; ++c)
      __builtin_amdgcn_global_load_lds(
          (const __attribute__((address_space(1))) void*)(s0 + (size_t)(c << 6) * lda),
          (__attribute__((address_space(3))) void*)((char*)&lA[buf][h][0] + (c << 13) + (tid << 4)),
          16, 0, 0);
  };
  auto stB = [&](int buf, int h, int tt) {
    int ttc = tt < nt ? tt : nt - 1;
    const unsigned short* s0 = bS + (size_t)(h << 7) * ldb + (ttc << 6);
#pragma unroll
    for (int c = 0; c < 2; ++c)
      __builtin_amdgcn_global_load_lds(
          (const __attribute__((address_space(1))) void*)(s0 + (size_t)(c << 6) * ldb),
          (__attribute__((address_space(3))) void*)((char*)&lB[buf][h][0] + (c << 13) + (tid << 4)),
          16, 0, 0);
  };

  f32x4 acc[8][4];
#pragma unroll
  for (int i = 0; i < 8; ++i)
#pragma unroll
    for (int j = 0; j < 4; ++j) acc[i][j] = f32x4{0.f, 0.f, 0.f, 0.f};

  // prologue: tile0 (8 ops) + B(1)h0, A(1)h1; vmcnt(4) -> tile0 landed
  stA(0, 0, 0); stB(0, 0, 0); stA(0, 1, 0); stB(0, 1, 0); stB(1, 0, 1); stA(1, 1, 1);
  asm volatile("s_waitcnt vmcnt(4)" ::: "memory");
  __builtin_amdgcn_s_barrier();

  for (int t = 0; t < nt; ++t) {
    const int buf = t & 1;
    const char* Ab0 = (const char*)&lA[buf][0][0];
    const char* Ab1 = (const char*)&lA[buf][1][0];
    const char* Bb0 = (const char*)&lB[buf][0][0];
    const char* Bb1 = (const char*)&lB[buf][1][0];

    short8 a0[4][2], a1[4][2], b0[2][2], b1[2][2];

    // q0: read a0(8)+b0(4); stage B(t+1)h1; MFMA quad (0,0)
    RD_A(a0, Ab0);
    RD_B(b0, Bb0);
    stB((t + 1) & 1, 1, t + 1);
    __builtin_amdgcn_s_barrier();
    MFMA16(a0, b0, 0, 0);
    __builtin_amdgcn_s_barrier();

    // q1: read a1(8); stage A(t+1)h0; MFMA quad (1,0)  (reuse b0)
    RD_A(a1, Ab1);
    stA((t + 1) & 1, 0, t + 1);
    __builtin_amdgcn_s_barrier();
    MFMA16(a1, b0, 4, 0);
    __builtin_amdgcn_s_barrier();

    // q2: read b1(4); stage B(t+2)h0 (last read of lB[buf][0] was q0); MFMA (1,1)
    RD_B(b1, Bb1);
    stB(buf, 0, t + 2);
    __builtin_amdgcn_s_barrier();
    MFMA16(a1, b1, 4, 2);
    __builtin_amdgcn_s_barrier();

    // q3: stage A(t+2)h1 (last read of lA[buf][1] was q1); vmcnt(4) = tile t+1
    // fully landed (only q2/q3 stages in flight); MFMA (0,1) (reuse a0,b1)
    stA(buf, 1, t + 2);
    asm volatile("s_waitcnt vmcnt(4)" ::: "memory");
    __builtin_amdgcn_s_barrier();
    MFMA16(a0, b1, 0, 2);
    __builtin_amdgcn_s_barrier();
  }
  asm volatile("s_waitcnt vmcnt(0)" ::: "memory");  // drain dummy tail stages

  // epilogue: C frag layout col=lane&15, row=(lane>>4)*4+reg
#pragma unroll
  for (int mig = 0; mig < 8; ++mig)
#pragma unroll
    for (int njg = 0; njg < 4; ++njg) {
      const int row = m0 + (mig >> 2) * 128 + wm * 64 + (mig & 3) * 16 + (kg << 2);
      const int col = n0 + (njg >> 1) * 128 + wn * 32 + (njg & 1) * 16 + fr;
      f32x4 v = acc[mig][njg];
      if (EPI == 1) {
        unsigned short* Ch = (unsigned short*)Cout + (size_t)z * sCz;
#pragma unroll
        for (int jj = 0; jj < 4; ++jj)
          Ch[(size_t)(row + jj) * ldc + col] = f2b(v[jj] * scale);
      } else if (EPI == 2) {
        float* Cf = (float*)Cout + (size_t)z * sCz;
        const float bb = bias[col];
#pragma unroll
        for (int jj = 0; jj < 4; ++jj)
          Cf[(size_t)(row + jj) * ldc + col] = v[jj] * scale + bb;
      } else if (EPI == 3) {
        unsigned short* Ch = (unsigned short*)Cout;
        const float bb = bias[col];
#pragma unroll
        for (int jj = 0; jj < 4; ++jj)
          Ch[(size_t)(row + jj) * ldc + col] = f2b(v[jj] + bb);
      } else if (EPI == 4) {   // bias by row (Vt-proj: row = output channel)
        unsigned short* Ch = (unsigned short*)Cout;
#pragma unroll
        for (int jj = 0; jj < 4; ++jj)
          Ch[(size_t)(row + jj) * ldc + col] = f2b(v[jj] + bias[row + jj]);
      } else {                 // EPI == 5: split-K bf16 partial
        unsigned short* Ch = (unsigned short*)Cout +
            (size_t)(zraw & 1) * 8388608 + (size_t)z * sCz;
#pragma unroll
        for (int jj = 0; jj < 4; ++jj)
          Ch[(size_t)(row + jj) * ldc + col] = f2b(v[jj]);
      }
    }
}

// ---------------- split-K reduce: attn = P0 + P1 (bf16) ----------------
__global__ __launch_bounds__(256)
void reduce_pv(const unsigned short* __restrict__ p0,
               const unsigned short* __restrict__ p1,
               unsigned short* __restrict__ out) {
  const size_t i = ((size_t)blockIdx.x * 256 + threadIdx.x) << 3;
  us8 a = *(const us8*)&p0[i];
  us8 b = *(const us8*)&p1[i];
  us8 o;
#pragma unroll
  for (int j = 0; j < 8; ++j) o[j] = f2b(b2f(a[j]) + b2f(b[j]));
  *(us8*)&out[i] = o;
}

// ---------------- causal softmax, in-place over bf16 rows ----------------
__global__ __launch_bounds__(256)
void softmax_causal(unsigned short* __restrict__ S, int T) {
  const int t = blockIdx.x, b = blockIdx.y;
  unsigned short* row = S + ((size_t)b * T + t) * T;
  const int tid  = threadIdx.x;
  const int lane = tid & 63;
  const int wid  = tid >> 6;
  const int base = tid << 3;   // 256 threads * 8 = 2048

  us8 raw = *(const us8*)&row[base];
  float v[8];
  float mx = -3.0e38f;
#pragma unroll
  for (int j = 0; j < 8; ++j) {
    const int s = base + j;
    v[j] = (s <= t) ? b2f(raw[j]) : -3.0e38f;
    mx = fmaxf(mx, v[j]);
  }
#pragma unroll
  for (int m = 32; m; m >>= 1) mx = fmaxf(mx, __shfl_xor(mx, m, 64));
  __shared__ float red[4];
  if (lane == 0) red[wid] = mx;
  __syncthreads();
  mx = fmaxf(fmaxf(red[0], red[1]), fmaxf(red[2], red[3]));

  float e[8];
  float sum = 0.f;
#pragma unroll
  for (int j = 0; j < 8; ++j) { e[j] = __expf(v[j] - mx); sum += e[j]; }
#pragma unroll
  for (int m = 32; m; m >>= 1) sum += __shfl_xor(sum, m, 64);
  __syncthreads();
  if (lane == 0) red[wid] = sum;
  __syncthreads();
  sum = red[0] + red[1] + red[2] + red[3];
  const float inv = 1.f / sum;

  us8 o;
#pragma unroll
  for (int j = 0; j < 8; ++j) o[j] = f2b(e[j] * inv);
  *(us8*)&row[base] = o;
}

// ---------------- host-side launch ----------------
extern "C" void kernel_launch(void* const* d_in, const int* in_sizes, int n_in,
                              void* d_out, int out_size, void* d_ws, size_t ws_size,
                              hipStream_t stream) {
  (void)in_sizes; (void)n_in; (void)out_size; (void)ws_size;
  const float* x  = (const float*)d_in[0];
  const float* Wq = (const float*)d_in[1];
  const float* bq = (const float*)d_in[2];
  const float* Wk = (const float*)d_in[3];
  const float* bk = (const float*)d_in[4];
  const float* Wv = (const float*)d_in[5];
  const float* bv = (const float*)d_in[6];
  const float* Wo = (const float*)d_in[7];
  const float* bo = (const float*)d_in[8];

  const int B = 4, T = 2048, C = 1024;
  const int M = B * T;                                   // 8192

  unsigned short* xb    = (unsigned short*)d_ws;         // M*C (later: attn)
  unsigned short* Wqkvb = xb    + (size_t)M * C;         // [Wq|Wk|Wv] packed
  unsigned short* Wob   = Wqkvb + (size_t)3 * C * C;     // C*C
  unsigned short* QK    = Wob   + (size_t)C * C;         // M*2C [Q|K]; later P0|P1
  unsigned short* Vt    = QK    + (size_t)M * 2 * C;     // [1024][8192] row-major
  unsigned short* S     = Vt    + (size_t)M * C;         // B*T*T (becomes P)
  float*          bws   = (float*)(S + (size_t)B * T * T); // 4096: bq|bk|bv|bo
  unsigned short* attn  = xb;                            // xb dead after Vt-proj
  unsigned short* P01   = QK;                            // QK dead after scores

  // 1. prep: converts + packing (one launch)
  prep_kernel<<<12304, 256, 0, stream>>>(x, Wq, Wk, Wv, Wo, bq, bk, bv, bo,
                                         xb, Wqkvb, Wob, bws);

  // 2a. QK projection: QK[t][0:2048] = x @ [Wq|Wk]^T + [bq|bk]
  gemm8<3, false, false><<<dim3(2 * C / 256, M / 256, 1), 512, 0, stream>>>(
      xb, Wqkvb, QK, bws, 1.f, C, C, C, 2 * C, 0LL, 0LL, 0LL);

  // 2b. Vt = Wv @ x^T + bv[row]: Vt[c][t_glob], row-major coalesced
  gemm8<4, false, false><<<dim3(M / 256, C / 256, 1), 512, 0, stream>>>(
      Wqkvb + (size_t)2 * C * C, xb, Vt, bws + 2 * C, 1.f, C, C, C, M,
      0LL, 0LL, 0LL);

  // 3. scores: S = Q K^T / 32 (bf16), lower-triangle 256-blocks only
  gemm8<1, false, true><<<dim3(T / 256, T / 256, B), 512, 0, stream>>>(
      QK, QK + C, S, nullptr, 0.03125f, C, 2 * C, 2 * C, T,
      (long long)T * 2 * C, (long long)T * 2 * C, (long long)T * T);

  // 4. causal softmax in-place (writes zeros above diagonal)
  softmax_causal<<<dim3(T, B), 256, 0, stream>>>(S, T);

  // 5. PV split-K=2: partials into P01 (= dead QK region)
  //    z = batch*2 + half; balanced halves of causally-clamped K
  gemm8<5, true, false><<<dim3(C / 256, T / 256, 2 * B), 512, 0, stream>>>(
      S, Vt, P01, nullptr, 1.f, T, T, M, C,
      (long long)T * T, 2048LL, (long long)T * C);

  // 6. reduce: attn = P0 + P1  (8.4M bf16 elems)
  reduce_pv<<<4096, 256, 0, stream>>>(P01, P01 + (size_t)M * C, attn);

  // 7. out = attn Wo^T + bo (f32)
  gemm8<2, false, false><<<dim3(C / 256, M / 256, 1), 512, 0, stream>>>(
      attn, Wob, d_out, bws + 3 * C, 1.f, C, C, C, C, 0LL, 0LL, 0LL);
}

// Round 7
// 191.702 us; speedup vs baseline: 1.6508x; 1.0794x over previous
//
#include <hip/hip_runtime.h>

// Masked self-attention, B=4 T=2048 C=1024 (single head, head dim = C).
// All GEMMs: 256x256 / BK=64 / 8-wave register-resident bf16 MFMA with a
// 4-barrier pipelined K-loop: per quadrant {RD next frags || MFMA current},
// stages (global_load_lds) interleaved, ONE counted vmcnt(4) per K-tile.
// LDS swizzle: 16B-slot ^= (row&7), applied both-sides. T1 XCD swizzle.
// Softmax is FUSED: scores epilogue writes e=exp(s/32) (causal-masked) and
// atomically accumulates row sums; the split-K reduce divides by rowsum.
// Pipeline: prep | QK-proj | Vt-proj | scores+exp+rowsum | PV split-K=2 |
//           reduce(/rowsum) | out-proj.

typedef __attribute__((ext_vector_type(8))) short short8;
typedef __attribute__((ext_vector_type(4))) float f32x4;
typedef __attribute__((ext_vector_type(4))) unsigned short us4;
typedef __attribute__((ext_vector_type(8))) unsigned short us8;
typedef __attribute__((ext_vector_type(4))) float fl4;

__device__ __forceinline__ unsigned short f2b(float f) {
  unsigned int u = __builtin_bit_cast(unsigned int, f);
  u += 0x7fffu + ((u >> 16) & 1u);   // round-to-nearest-even
  return (unsigned short)(u >> 16);
}
__device__ __forceinline__ float b2f(unsigned short h) {
  unsigned int u = ((unsigned int)h) << 16;
  return __builtin_bit_cast(float, u);
}

// ---------------- merged prep: converts + bias packing + rowsum zero -------
// blocks [0,8192): x -> xb ; [8192,12288): weights ; 12288..: biases; 12304: rowsum=0
__global__ __launch_bounds__(256) void prep_kernel(
    const float* __restrict__ x,
    const float* __restrict__ Wq, const float* __restrict__ Wk,
    const float* __restrict__ Wv, const float* __restrict__ Wo,
    const float* __restrict__ bq, const float* __restrict__ bk,
    const float* __restrict__ bv, const float* __restrict__ bo,
    unsigned short* __restrict__ xb, unsigned short* __restrict__ Wqkvb,
    unsigned short* __restrict__ Wob, float* __restrict__ bws,
    float* __restrict__ rows) {
  const int bid = blockIdx.x;
  if (bid < 8192) {
    const int i = bid * 256 + threadIdx.x;
    fl4 f = *(const fl4*)&x[(size_t)i << 2];
    us4 o;
#pragma unroll
    for (int j = 0; j < 4; ++j) o[j] = f2b(f[j]);
    *(us4*)&xb[(size_t)i << 2] = o;
  } else if (bid < 12288) {
    const int w = (bid - 8192) >> 10;
    const int i = ((bid - 8192) & 1023) * 256 + threadIdx.x;
    const float* s = w == 0 ? Wq : w == 1 ? Wk : w == 2 ? Wv : Wo;
    unsigned short* d = w < 3 ? Wqkvb + (size_t)w * 1024 * 1024 : Wob;
    fl4 f = *(const fl4*)&s[(size_t)i << 2];
    us4 o;
#pragma unroll
    for (int j = 0; j < 4; ++j) o[j] = f2b(f[j]);
    *(us4*)&d[(size_t)i << 2] = o;
  } else if (bid < 12304) {
    const int i = (bid - 12288) * 256 + threadIdx.x;   // 4096
    const int sel = i >> 10, idx = i & 1023;
    const float* p = sel == 0 ? bq : sel == 1 ? bk : sel == 2 ? bv : bo;
    bws[i] = p[idx];
  } else {
    for (int k = threadIdx.x; k < 8192; k += 256) rows[k] = 0.f;
  }
}

// ---------------- 256x256 4-barrier pipelined B^T GEMM ----------------
// C[m][n] = scale * sum_k A[m][k]*B[n][k]. A,B bf16 k-contiguous.
// 512 threads = 8 waves (2M x 4N); per-wave output 128x64.
// EPI: 2 = f32 *scale + bias[col]   3 = bf16 + bias[col]
//      4 = bf16 + bias[row]         5 = bf16 split-K partial -> P0|P1
//      6 = scores: bf16 exp(v*scale) causal-masked + rowsum atomics

#define RD_A(dst, basep)                                                   \
  _Pragma("unroll") for (int mi = 0; mi < 4; ++mi)                         \
  _Pragma("unroll") for (int ks = 0; ks < 2; ++ks)                         \
      dst[mi][ks] = *(const short8*)((basep) + offA[mi][ks]);

#define RD_B(dst, basep)                                                   \
  _Pragma("unroll") for (int nj = 0; nj < 2; ++nj)                         \
  _Pragma("unroll") for (int ks = 0; ks < 2; ++ks)                         \
      dst[nj][ks] = *(const short8*)((basep) + offB[nj][ks]);

#define MFMA16(AF, BF, MI0, NJ0)                                           \
  __builtin_amdgcn_s_setprio(1);                                           \
  _Pragma("unroll") for (int ks = 0; ks < 2; ++ks)                         \
  _Pragma("unroll") for (int mi = 0; mi < 4; ++mi)                         \
  _Pragma("unroll") for (int nj = 0; nj < 2; ++nj)                         \
      acc[(MI0) + mi][(NJ0) + nj] = __builtin_amdgcn_mfma_f32_16x16x32_bf16( \
          AF[mi][ks], BF[nj][ks], acc[(MI0) + mi][(NJ0) + nj], 0, 0, 0);   \
  __builtin_amdgcn_s_setprio(0);

template<int EPI, bool SPLIT, bool SKIP_UPPER>
__global__ __launch_bounds__(512, 2)
void gemm8(const unsigned short* __restrict__ A, const unsigned short* __restrict__ B,
           void* __restrict__ Cout, const float* __restrict__ bias,
           float* __restrict__ rows, float scale, int K,
           int lda, int ldb, int ldc,
           long long sAz, long long sBz, long long sCz)
{
  // T1: XCD-bijective block swizzle (all grids have nwg % 8 == 0)
  const int gx = gridDim.x;
  const int nwg = gx * gridDim.y;
  int flat = blockIdx.y * gx + blockIdx.x;
  { const int q = nwg >> 3, r = nwg & 7, xc = flat & 7, i = flat >> 3;
    flat = (xc < r ? xc * (q + 1) : r * (q + 1) + (xc - r) * q) + i; }
  const int m0 = (flat / gx) << 8;
  const int n0 = (flat % gx) << 8;
  if (SKIP_UPPER && n0 > m0 + 255) return;   // fully-masked score block
  const int zraw = blockIdx.z;
  const int z = SPLIT ? (zraw >> 1) : zraw;

  int kBeg = 0, kEnd = K;
  if (SPLIT) {                      // balanced causal split (PV)
    const int kFull = m0 + 256;
    const int kMid = kFull >> 1;    // multiple of 128
    kBeg = (zraw & 1) ? kMid : 0;
    kEnd = (zraw & 1) ? kFull : kMid;
  }
  const int nt = (kEnd - kBeg) >> 6;

  __shared__ unsigned short lA[2][2][8192];  // [dbuf][half][128*64]
  __shared__ unsigned short lB[2][2][8192];

  const int tid = threadIdx.x, lane = tid & 63, wid = tid >> 6;
  const int wm = wid >> 2, wn = wid & 3;     // 2 x 4 waves
  const int fr = lane & 15, kg = lane >> 4;

  const unsigned short* Ab = A + (size_t)z * sAz;
  const unsigned short* Bb = B + (size_t)z * sBz;

  // ds_read byte offsets within a 16KB half; 16B-slot index XOR row&7
  const int xorv = (fr & 7) << 4;
  int offA[4][2], offB[2][2];
#pragma unroll
  for (int mi = 0; mi < 4; ++mi)
#pragma unroll
    for (int ks = 0; ks < 2; ++ks)
      offA[mi][ks] = ((wm << 6) + (mi << 4) + fr) * 128 + (((ks << 6) + (kg << 4)) ^ xorv);
#pragma unroll
  for (int nj = 0; nj < 2; ++nj)
#pragma unroll
    for (int ks = 0; ks < 2; ++ks)
      offB[nj][ks] = ((wn << 5) + (nj << 4) + fr) * 128 + (((ks << 6) + (kg << 4)) ^ xorv);

  // staging: dest linear; source slot inverse-swizzled
  const int srow = tid >> 3;
  const int scol = (((tid & 7) ^ (srow & 7)) << 3);
  const unsigned short* aS = Ab + (size_t)(m0 + srow) * lda + scol + kBeg;
  const unsigned short* bS = Bb + (size_t)(n0 + srow) * ldb + scol + kBeg;

  auto stA = [&](int buf, int h, int tt) {
    int ttc = tt < nt ? tt : nt - 1;
    const unsigned short* s0 = aS + (size_t)(h << 7) * lda + (ttc << 6);
#pragma unroll
    for (int c = 0; c < 2; ++c)
      __builtin_amdgcn_global_load_lds(
          (const __attribute__((address_space(1))) void*)(s0 + (size_t)(c << 6) * lda),
          (__attribute__((address_space(3))) void*)((char*)&lA[buf][h][0] + (c << 13) + (tid << 4)),
          16, 0, 0);
  };
  auto stB = [&](int buf, int h, int tt) {
    int ttc = tt < nt ? tt : nt - 1;
    const unsigned short* s0 = bS + (size_t)(h << 7) * ldb + (ttc << 6);
#pragma unroll
    for (int c = 0; c < 2; ++c)
      __builtin_amdgcn_global_load_lds(
          (const __attribute__((address_space(1))) void*)(s0 + (size_t)(c << 6) * ldb),
          (__attribute__((address_space(3))) void*)((char*)&lB[buf][h][0] + (c << 13) + (tid << 4)),
          16, 0, 0);
  };

  f32x4 acc[8][4];
#pragma unroll
  for (int i = 0; i < 8; ++i)
#pragma unroll
    for (int j = 0; j < 4; ++j) acc[i][j] = f32x4{0.f, 0.f, 0.f, 0.f};

  // prologue: tile0 (8 ops) + B(1)h0, A(1)h1; vmcnt(4) -> tile0 landed
  stA(0, 0, 0); stB(0, 0, 0); stA(0, 1, 0); stB(0, 1, 0); stB(1, 0, 1); stA(1, 1, 1);
  asm volatile("s_waitcnt vmcnt(4)" ::: "memory");
  __builtin_amdgcn_s_barrier();

  for (int t = 0; t < nt; ++t) {
    const int buf = t & 1, nbuf = buf ^ 1;
    const char* Ab0 = (const char*)&lA[buf][0][0];
    const char* Ab1 = (const char*)&lA[buf][1][0];
    const char* Bb0 = (const char*)&lB[buf][0][0];
    const char* Bb1 = (const char*)&lB[buf][1][0];

    short8 a0[4][2], a1[4][2], b0[2][2], b1[2][2];

    // P0: read a0+b0; stage B(t+1)h1; BAR; then overlap a1-reads with MFMA(0,0)
    RD_A(a0, Ab0);
    RD_B(b0, Bb0);
    stB(nbuf, 1, t + 1);
    __builtin_amdgcn_s_barrier();
    RD_A(a1, Ab1);
    MFMA16(a0, b0, 0, 0);

    // P1: stage A(t+1)h0; BAR; b1-reads overlap MFMA(1,0)
    stA(nbuf, 0, t + 1);
    __builtin_amdgcn_s_barrier();
    RD_B(b1, Bb1);
    MFMA16(a1, b0, 4, 0);

    // P2: stage B(t+2)h0 (last reader of lB[buf][0] drained before BAR#0); BAR; MFMA(1,1)
    stB(buf, 0, t + 2);
    __builtin_amdgcn_s_barrier();
    MFMA16(a1, b1, 4, 2);

    // P3: stage A(t+2)h1; vmcnt(4) = tile t+1 fully landed; BAR; MFMA(0,1)
    stA(buf, 1, t + 2);
    asm volatile("s_waitcnt vmcnt(4)" ::: "memory");
    __builtin_amdgcn_s_barrier();
    MFMA16(a0, b1, 0, 2);
  }
  asm volatile("s_waitcnt vmcnt(0)" ::: "memory");  // drain dummy tail stages

  // epilogue: C frag layout col=lane&15, row=(lane>>4)*4+reg
  if (EPI == 6) {
    // scores: causal-masked exp, bf16 store, per-row sum -> atomics
    unsigned short* Ch = (unsigned short*)Cout + (size_t)z * sCz;
#pragma unroll
    for (int mig = 0; mig < 8; ++mig) {
      const int row = m0 + (mig >> 2) * 128 + wm * 64 + (mig & 3) * 16 + (kg << 2);
#pragma unroll
      for (int jj = 0; jj < 4; ++jj) {
        const int r = row + jj;
        float rs = 0.f;
#pragma unroll
        for (int njg = 0; njg < 4; ++njg) {
          const int col = n0 + (njg >> 1) * 128 + wn * 32 + (njg & 1) * 16 + fr;
          const float ee = (col <= r) ? __expf(acc[mig][njg][jj] * scale) : 0.f;
          rs += ee;
          Ch[(size_t)r * ldc + col] = f2b(ee);
        }
#pragma unroll
        for (int mk = 1; mk <= 8; mk <<= 1) rs += __shfl_xor(rs, mk, 64);
        if (fr == 0) atomicAdd(&rows[z * 2048 + r], rs);
      }
    }
    return;
  }
#pragma unroll
  for (int mig = 0; mig < 8; ++mig)
#pragma unroll
    for (int njg = 0; njg < 4; ++njg) {
      const int row = m0 + (mig >> 2) * 128 + wm * 64 + (mig & 3) * 16 + (kg << 2);
      const int col = n0 + (njg >> 1) * 128 + wn * 32 + (njg & 1) * 16 + fr;
      f32x4 v = acc[mig][njg];
      if (EPI == 2) {
        float* Cf = (float*)Cout + (size_t)z * sCz;
        const float bb = bias[col];
#pragma unroll
        for (int jj = 0; jj < 4; ++jj)
          Cf[(size_t)(row + jj) * ldc + col] = v[jj] * scale + bb;
      } else if (EPI == 3) {
        unsigned short* Ch = (unsigned short*)Cout;
        const float bb = bias[col];
#pragma unroll
        for (int jj = 0; jj < 4; ++jj)
          Ch[(size_t)(row + jj) * ldc + col] = f2b(v[jj] + bb);
      } else if (EPI == 4) {   // bias by row (Vt-proj: row = output channel)
        unsigned short* Ch = (unsigned short*)Cout;
#pragma unroll
        for (int jj = 0; jj < 4; ++jj)
          Ch[(size_t)(row + jj) * ldc + col] = f2b(v[jj] + bias[row + jj]);
      } else {                 // EPI == 5: split-K bf16 partial
        unsigned short* Ch = (unsigned short*)Cout +
            (size_t)(zraw & 1) * 8388608 + (size_t)z * sCz;
#pragma unroll
        for (int jj = 0; jj < 4; ++jj)
          Ch[(size_t)(row + jj) * ldc + col] = f2b(v[jj]);
      }
    }
}

// -------- split-K reduce + softmax normalize: attn = (P0+P1)/rowsum --------
__global__ __launch_bounds__(256)
void reduce_pv(const unsigned short* __restrict__ p0,
               const unsigned short* __restrict__ p1,
               const float* __restrict__ rows,
               unsigned short* __restrict__ out) {
  const size_t i = ((size_t)blockIdx.x * 256 + threadIdx.x) << 3;
  const float inv = 1.f / rows[i >> 10];
  us8 a = *(const us8*)&p0[i];
  us8 b = *(const us8*)&p1[i];
  us8 o;
#pragma unroll
  for (int j = 0; j < 8; ++j) o[j] = f2b((b2f(a[j]) + b2f(b[j])) * inv);
  *(us8*)&out[i] = o;
}

// ---------------- host-side launch ----------------
extern "C" void kernel_launch(void* const* d_in, const int* in_sizes, int n_in,
                              void* d_out, int out_size, void* d_ws, size_t ws_size,
                              hipStream_t stream) {
  (void)in_sizes; (void)n_in; (void)out_size; (void)ws_size;
  const float* x  = (const float*)d_in[0];
  const float* Wq = (const float*)d_in[1];
  const float* bq = (const float*)d_in[2];
  const float* Wk = (const float*)d_in[3];
  const float* bk = (const float*)d_in[4];
  const float* Wv = (const float*)d_in[5];
  const float* bv = (const float*)d_in[6];
  const float* Wo = (const float*)d_in[7];
  const float* bo = (const float*)d_in[8];

  const int B = 4, T = 2048, C = 1024;
  const int M = B * T;                                   // 8192

  unsigned short* xb    = (unsigned short*)d_ws;         // M*C (later: attn)
  unsigned short* Wqkvb = xb    + (size_t)M * C;         // [Wq|Wk|Wv] packed
  unsigned short* Wob   = Wqkvb + (size_t)3 * C * C;     // C*C
  unsigned short* QK    = Wob   + (size_t)C * C;         // M*2C [Q|K]; later P0|P1
  unsigned short* Vt    = QK    + (size_t)M * 2 * C;     // [1024][8192] row-major
  unsigned short* S     = Vt    + (size_t)M * C;         // B*T*T (e values)
  float*          bws   = (float*)(S + (size_t)B * T * T); // 4096: bq|bk|bv|bo
  float*          rowsum= bws + 4096;                    // 8192 f32
  unsigned short* attn  = xb;                            // xb dead after Vt-proj
  unsigned short* P01   = QK;                            // QK dead after scores

  // 1. prep: converts + packing + rowsum zero (one launch)
  prep_kernel<<<12305, 256, 0, stream>>>(x, Wq, Wk, Wv, Wo, bq, bk, bv, bo,
                                         xb, Wqkvb, Wob, bws, rowsum);

  // 2a. QK projection: QK[t][0:2048] = x @ [Wq|Wk]^T + [bq|bk]
  gemm8<3, false, false><<<dim3(2 * C / 256, M / 256, 1), 512, 0, stream>>>(
      xb, Wqkvb, QK, bws, nullptr, 1.f, C, C, C, 2 * C, 0LL, 0LL, 0LL);

  // 2b. Vt = Wv @ x^T + bv[row]: Vt[c][t_glob], row-major coalesced
  gemm8<4, false, false><<<dim3(M / 256, C / 256, 1), 512, 0, stream>>>(
      Wqkvb + (size_t)2 * C * C, xb, Vt, bws + 2 * C, nullptr, 1.f, C, C, C, M,
      0LL, 0LL, 0LL);

  // 3. scores: S = exp(Q K^T / 32) causal-masked (bf16) + rowsum atomics
  gemm8<6, false, true><<<dim3(T / 256, T / 256, B), 512, 0, stream>>>(
      QK, QK + C, S, nullptr, rowsum, 0.03125f, C, 2 * C, 2 * C, T,
      (long long)T * 2 * C, (long long)T * 2 * C, (long long)T * T);

  // 4. PV split-K=2: partials into P01 (= dead QK region)
  gemm8<5, true, false><<<dim3(C / 256, T / 256, 2 * B), 512, 0, stream>>>(
      S, Vt, P01, nullptr, nullptr, 1.f, T, T, M, C,
      (long long)T * T, 2048LL, (long long)T * C);

  // 5. reduce + normalize: attn = (P0 + P1) / rowsum
  reduce_pv<<<4096, 256, 0, stream>>>(P01, P01 + (size_t)M * C, rowsum, attn);

  // 6. out = attn Wo^T + bo (f32)
  gemm8<2, false, false><<<dim3(C / 256, M / 256, 1), 512, 0, stream>>>(
      attn, Wob, d_out, bws + 3 * C, nullptr, 1.f, C, C, C, C, 0LL, 0LL, 0LL);
}

// Round 8
// 188.145 us; speedup vs baseline: 1.6820x; 1.0189x over previous
//
#include <hip/hip_runtime.h>

// Masked self-attention, B=4 T=2048 C=1024 (single head, head dim = C).
// gemm8 : 256x256 / BK=64 / 8-wave 4-phase pipelined bf16 MFMA (unchanged
//         from round 7; reads 12/8/4/0 per phase, one vmcnt(4)/K-tile).
// gemm2ph: 256x128 / BK=64 / 8-wave 2-phase variant (full-machine grids for
//         the N=1024-limited GEMMs). Counted vmcnt(4)/(2) before each BAR.
// LDS swizzle both kernels: 16B-slot ^= (row&7), applied both-sides.
// Softmax fused into scores epilogue (exp + rowsum atomics); PV split-K=4
// partials -> reduce_pv4 divides by rowsum.
// Pipeline: prep | QK-proj(gemm8) | Vt-proj(gemm2ph) | scores+exp(gemm8) |
//           PV splitK4(gemm8) | reduce4 | out-proj(gemm2ph).

typedef __attribute__((ext_vector_type(8))) short short8;
typedef __attribute__((ext_vector_type(4))) float f32x4;
typedef __attribute__((ext_vector_type(4))) unsigned short us4;
typedef __attribute__((ext_vector_type(8))) unsigned short us8;
typedef __attribute__((ext_vector_type(4))) float fl4;

__device__ __forceinline__ unsigned short f2b(float f) {
  unsigned int u = __builtin_bit_cast(unsigned int, f);
  u += 0x7fffu + ((u >> 16) & 1u);   // round-to-nearest-even
  return (unsigned short)(u >> 16);
}
__device__ __forceinline__ float b2f(unsigned short h) {
  unsigned int u = ((unsigned int)h) << 16;
  return __builtin_bit_cast(float, u);
}

// ---------------- merged prep: converts + bias packing + rowsum zero -------
__global__ __launch_bounds__(256) void prep_kernel(
    const float* __restrict__ x,
    const float* __restrict__ Wq, const float* __restrict__ Wk,
    const float* __restrict__ Wv, const float* __restrict__ Wo,
    const float* __restrict__ bq, const float* __restrict__ bk,
    const float* __restrict__ bv, const float* __restrict__ bo,
    unsigned short* __restrict__ xb, unsigned short* __restrict__ Wqkvb,
    unsigned short* __restrict__ Wob, float* __restrict__ bws,
    float* __restrict__ rows) {
  const int bid = blockIdx.x;
  if (bid < 8192) {
    const int i = bid * 256 + threadIdx.x;
    fl4 f = *(const fl4*)&x[(size_t)i << 2];
    us4 o;
#pragma unroll
    for (int j = 0; j < 4; ++j) o[j] = f2b(f[j]);
    *(us4*)&xb[(size_t)i << 2] = o;
  } else if (bid < 12288) {
    const int w = (bid - 8192) >> 10;
    const int i = ((bid - 8192) & 1023) * 256 + threadIdx.x;
    const float* s = w == 0 ? Wq : w == 1 ? Wk : w == 2 ? Wv : Wo;
    unsigned short* d = w < 3 ? Wqkvb + (size_t)w * 1024 * 1024 : Wob;
    fl4 f = *(const fl4*)&s[(size_t)i << 2];
    us4 o;
#pragma unroll
    for (int j = 0; j < 4; ++j) o[j] = f2b(f[j]);
    *(us4*)&d[(size_t)i << 2] = o;
  } else if (bid < 12304) {
    const int i = (bid - 12288) * 256 + threadIdx.x;
    const int sel = i >> 10, idx = i & 1023;
    const float* p = sel == 0 ? bq : sel == 1 ? bk : sel == 2 ? bv : bo;
    bws[i] = p[idx];
  } else {
    for (int k = threadIdx.x; k < 8192; k += 256) rows[k] = 0.f;
  }
}

#define RD_A(dst, basep)                                                   \
  _Pragma("unroll") for (int mi = 0; mi < 4; ++mi)                         \
  _Pragma("unroll") for (int ks = 0; ks < 2; ++ks)                         \
      dst[mi][ks] = *(const short8*)((basep) + offA[mi][ks]);

#define RD_B(dst, basep)                                                   \
  _Pragma("unroll") for (int nj = 0; nj < 2; ++nj)                         \
  _Pragma("unroll") for (int ks = 0; ks < 2; ++ks)                         \
      dst[nj][ks] = *(const short8*)((basep) + offB[nj][ks]);

#define MFMA16(AF, BF, MI0, NJ0)                                           \
  __builtin_amdgcn_s_setprio(1);                                           \
  _Pragma("unroll") for (int ks = 0; ks < 2; ++ks)                         \
  _Pragma("unroll") for (int mi = 0; mi < 4; ++mi)                         \
  _Pragma("unroll") for (int nj = 0; nj < 2; ++nj)                         \
      acc[(MI0) + mi][(NJ0) + nj] = __builtin_amdgcn_mfma_f32_16x16x32_bf16( \
          AF[mi][ks], BF[nj][ks], acc[(MI0) + mi][(NJ0) + nj], 0, 0, 0);   \
  __builtin_amdgcn_s_setprio(0);

// ---------------- 256x256 4-phase pipelined B^T GEMM (as round 7) ----------
// EPI: 3 = bf16 + bias[col]   5 = split-K4 bf16 partial (q -> 4 buffers)
//      6 = scores: bf16 exp(v*scale) causal-masked + rowsum atomics
template<int EPI, bool SPLIT4, bool SKIP_UPPER>
__global__ __launch_bounds__(512, 2)
void gemm8(const unsigned short* __restrict__ A, const unsigned short* __restrict__ B,
           void* __restrict__ Cout, const float* __restrict__ bias,
           float* __restrict__ rows, float scale, int K,
           int lda, int ldb, int ldc,
           long long sAz, long long sBz, long long sCz)
{
  const int gx = gridDim.x;
  const int nwg = gx * gridDim.y;
  int flat = blockIdx.y * gx + blockIdx.x;
  { const int q = nwg >> 3, r = nwg & 7, xc = flat & 7, i = flat >> 3;
    flat = (xc < r ? xc * (q + 1) : r * (q + 1) + (xc - r) * q) + i; }
  const int m0 = (flat / gx) << 8;
  const int n0 = (flat % gx) << 8;
  if (SKIP_UPPER && n0 > m0 + 255) return;
  const int zraw = blockIdx.z;
  const int z = SPLIT4 ? (zraw >> 2) : zraw;

  int kBeg = 0, kEnd = K;
  if (SPLIT4) {                        // balanced causal quarter (PV)
    const int quarter = (m0 + 256) >> 2;       // multiple of 64
    kBeg = (zraw & 3) * quarter;
    kEnd = kBeg + quarter;
  }
  const int nt = (kEnd - kBeg) >> 6;

  __shared__ unsigned short lA[2][2][8192];
  __shared__ unsigned short lB[2][2][8192];

  const int tid = threadIdx.x, lane = tid & 63, wid = tid >> 6;
  const int wm = wid >> 2, wn = wid & 3;
  const int fr = lane & 15, kg = lane >> 4;

  const unsigned short* Ab = A + (size_t)z * sAz;
  const unsigned short* Bb = B + (size_t)z * sBz;

  const int xorv = (fr & 7) << 4;
  int offA[4][2], offB[2][2];
#pragma unroll
  for (int mi = 0; mi < 4; ++mi)
#pragma unroll
    for (int ks = 0; ks < 2; ++ks)
      offA[mi][ks] = ((wm << 6) + (mi << 4) + fr) * 128 + (((ks << 6) + (kg << 4)) ^ xorv);
#pragma unroll
  for (int nj = 0; nj < 2; ++nj)
#pragma unroll
    for (int ks = 0; ks < 2; ++ks)
      offB[nj][ks] = ((wn << 5) + (nj << 4) + fr) * 128 + (((ks << 6) + (kg << 4)) ^ xorv);

  const int srow = tid >> 3;
  const int scol = (((tid & 7) ^ (srow & 7)) << 3);
  const unsigned short* aS = Ab + (size_t)(m0 + srow) * lda + scol + kBeg;
  const unsigned short* bS = Bb + (size_t)(n0 + srow) * ldb + scol + kBeg;

  auto stA = [&](int buf, int h, int tt) {
    int ttc = tt < nt ? tt : nt - 1;
    const unsigned short* s0 = aS + (size_t)(h << 7) * lda + (ttc << 6);
#pragma unroll
    for (int c = 0; c < 2; ++c)
      __builtin_amdgcn_global_load_lds(
          (const __attribute__((address_space(1))) void*)(s0 + (size_t)(c << 6) * lda),
          (__attribute__((address_space(3))) void*)((char*)&lA[buf][h][0] + (c << 13) + (tid << 4)),
          16, 0, 0);
  };
  auto stB = [&](int buf, int h, int tt) {
    int ttc = tt < nt ? tt : nt - 1;
    const unsigned short* s0 = bS + (size_t)(h << 7) * ldb + (ttc << 6);
#pragma unroll
    for (int c = 0; c < 2; ++c)
      __builtin_amdgcn_global_load_lds(
          (const __attribute__((address_space(1))) void*)(s0 + (size_t)(c << 6) * ldb),
          (__attribute__((address_space(3))) void*)((char*)&lB[buf][h][0] + (c << 13) + (tid << 4)),
          16, 0, 0);
  };

  f32x4 acc[8][4];
#pragma unroll
  for (int i = 0; i < 8; ++i)
#pragma unroll
    for (int j = 0; j < 4; ++j) acc[i][j] = f32x4{0.f, 0.f, 0.f, 0.f};

  stA(0, 0, 0); stB(0, 0, 0); stA(0, 1, 0); stB(0, 1, 0); stB(1, 0, 1); stA(1, 1, 1);
  asm volatile("s_waitcnt vmcnt(4)" ::: "memory");
  __builtin_amdgcn_s_barrier();

  for (int t = 0; t < nt; ++t) {
    const int buf = t & 1, nbuf = buf ^ 1;
    const char* Ab0 = (const char*)&lA[buf][0][0];
    const char* Ab1 = (const char*)&lA[buf][1][0];
    const char* Bb0 = (const char*)&lB[buf][0][0];
    const char* Bb1 = (const char*)&lB[buf][1][0];

    short8 a0[4][2], a1[4][2], b0[2][2], b1[2][2];

    RD_A(a0, Ab0);
    RD_B(b0, Bb0);
    stB(nbuf, 1, t + 1);
    __builtin_amdgcn_s_barrier();
    RD_A(a1, Ab1);
    MFMA16(a0, b0, 0, 0);

    stA(nbuf, 0, t + 1);
    __builtin_amdgcn_s_barrier();
    RD_B(b1, Bb1);
    MFMA16(a1, b0, 4, 0);

    stB(buf, 0, t + 2);
    __builtin_amdgcn_s_barrier();
    MFMA16(a1, b1, 4, 2);

    stA(buf, 1, t + 2);
    asm volatile("s_waitcnt vmcnt(4)" ::: "memory");
    __builtin_amdgcn_s_barrier();
    MFMA16(a0, b1, 0, 2);
  }
  asm volatile("s_waitcnt vmcnt(0)" ::: "memory");

  if (EPI == 6) {
    unsigned short* Ch = (unsigned short*)Cout + (size_t)z * sCz;
#pragma unroll
    for (int mig = 0; mig < 8; ++mig) {
      const int row = m0 + (mig >> 2) * 128 + wm * 64 + (mig & 3) * 16 + (kg << 2);
#pragma unroll
      for (int jj = 0; jj < 4; ++jj) {
        const int r = row + jj;
        float rs = 0.f;
#pragma unroll
        for (int njg = 0; njg < 4; ++njg) {
          const int col = n0 + (njg >> 1) * 128 + wn * 32 + (njg & 1) * 16 + fr;
          const float ee = (col <= r) ? __expf(acc[mig][njg][jj] * scale) : 0.f;
          rs += ee;
          Ch[(size_t)r * ldc + col] = f2b(ee);
        }
#pragma unroll
        for (int mk = 1; mk <= 8; mk <<= 1) rs += __shfl_xor(rs, mk, 64);
        if (fr == 0) atomicAdd(&rows[z * 2048 + r], rs);
      }
    }
    return;
  }
#pragma unroll
  for (int mig = 0; mig < 8; ++mig)
#pragma unroll
    for (int njg = 0; njg < 4; ++njg) {
      const int row = m0 + (mig >> 2) * 128 + wm * 64 + (mig & 3) * 16 + (kg << 2);
      const int col = n0 + (njg >> 1) * 128 + wn * 32 + (njg & 1) * 16 + fr;
      f32x4 v = acc[mig][njg];
      if (EPI == 3) {
        unsigned short* Ch = (unsigned short*)Cout;
        const float bb = bias[col];
#pragma unroll
        for (int jj = 0; jj < 4; ++jj)
          Ch[(size_t)(row + jj) * ldc + col] = f2b(v[jj] + bb);
      } else {   // EPI == 5: split-K4 partial; q selects buffer
        const int q = zraw & 3;
        unsigned short* Ch =
            (q == 0) ? (unsigned short*)Cout :
            (q == 1) ? (unsigned short*)Cout + 8388608 :
            (q == 2) ? (unsigned short*)bias :       // P2 buffer (cast)
                       (unsigned short*)rows;        // P3 buffer (cast)
        Ch += (size_t)z * sCz;
#pragma unroll
        for (int jj = 0; jj < 4; ++jj)
          Ch[(size_t)(row + jj) * ldc + col] = f2b(v[jj]);
      }
    }
}

// ---------------- 256x128 2-phase pipelined B^T GEMM ----------------
// Full-machine grids for N(or M)=1024 GEMMs. 8 waves (2M x 4N), per-wave
// output 128x32. Phases: {reads; stage; counted vmcnt; BAR; 16 MFMA}.
// EPI: 2 = f32 + bias[col]   4 = bf16 + bias[row]
template<int EPI>
__global__ __launch_bounds__(512, 2)
void gemm2ph(const unsigned short* __restrict__ A, const unsigned short* __restrict__ B,
             void* __restrict__ Cout, const float* __restrict__ bias,
             int K, int lda, int ldb, int ldc)
{
  const int gx = gridDim.x;
  const int nwg = gx * gridDim.y;
  int flat = blockIdx.y * gx + blockIdx.x;
  { const int q = nwg >> 3, r = nwg & 7, xc = flat & 7, i = flat >> 3;
    flat = (xc < r ? xc * (q + 1) : r * (q + 1) + (xc - r) * q) + i; }
  const int m0 = (flat / gx) << 8;
  const int n0 = (flat % gx) << 7;
  const int nt = K >> 6;

  __shared__ unsigned short lA[2][2][8192];   // 64 KB
  __shared__ unsigned short lB[2][8192];      // 32 KB (128 rows x 64)

  const int tid = threadIdx.x, lane = tid & 63, wid = tid >> 6;
  const int wm = wid >> 2, wn = wid & 3;
  const int fr = lane & 15, kg = lane >> 4;

  const int xorv = (fr & 7) << 4;
  int offA[4][2], offB[2][2];
#pragma unroll
  for (int mi = 0; mi < 4; ++mi)
#pragma unroll
    for (int ks = 0; ks < 2; ++ks)
      offA[mi][ks] = ((wm << 6) + (mi << 4) + fr) * 128 + (((ks << 6) + (kg << 4)) ^ xorv);
#pragma unroll
  for (int nj = 0; nj < 2; ++nj)
#pragma unroll
    for (int ks = 0; ks < 2; ++ks)
      offB[nj][ks] = ((wn << 5) + (nj << 4) + fr) * 128 + (((ks << 6) + (kg << 4)) ^ xorv);

  const int srow = tid >> 3;
  const int scol = (((tid & 7) ^ (srow & 7)) << 3);
  const unsigned short* aS = A + (size_t)(m0 + srow) * lda + scol;
  const unsigned short* bS = B + (size_t)(n0 + srow) * ldb + scol;

  auto stA = [&](int buf, int h, int tt) {
    int ttc = tt < nt ? tt : nt - 1;
    const unsigned short* s0 = aS + (size_t)(h << 7) * lda + (ttc << 6);
#pragma unroll
    for (int c = 0; c < 2; ++c)
      __builtin_amdgcn_global_load_lds(
          (const __attribute__((address_space(1))) void*)(s0 + (size_t)(c << 6) * lda),
          (__attribute__((address_space(3))) void*)((char*)&lA[buf][h][0] + (c << 13) + (tid << 4)),
          16, 0, 0);
  };
  auto stB = [&](int buf, int tt) {   // whole 128x64 B tile (2 insts)
    int ttc = tt < nt ? tt : nt - 1;
    const unsigned short* s0 = bS + (ttc << 6);
#pragma unroll
    for (int c = 0; c < 2; ++c)
      __builtin_amdgcn_global_load_lds(
          (const __attribute__((address_space(1))) void*)(s0 + (size_t)(c << 6) * ldb),
          (__attribute__((address_space(3))) void*)((char*)&lB[buf][0] + (c << 13) + (tid << 4)),
          16, 0, 0);
  };

  f32x4 acc[8][2];
#pragma unroll
  for (int i = 0; i < 8; ++i)
#pragma unroll
    for (int j = 0; j < 2; ++j) acc[i][j] = f32x4{0.f, 0.f, 0.f, 0.f};

  // prologue: tile0 B+h0+h1 (6 loads); wait B+h0 (leave h1 flying)
  stB(0, 0); stA(0, 0, 0); stA(0, 1, 0);
  asm volatile("s_waitcnt vmcnt(2)" ::: "memory");
  __builtin_amdgcn_s_barrier();

  for (int t = 0; t < nt; ++t) {
    const int buf = t & 1, nbuf = buf ^ 1;
    const char* Ab0 = (const char*)&lA[buf][0][0];
    const char* Ab1 = (const char*)&lA[buf][1][0];
    const char* Bbp = (const char*)&lB[buf][0];

    short8 a0[4][2], a1[4][2], b0[2][2];

    // q0: reads B+h0; stage t+1 B+h0 (4); vmcnt(4) waits t's h1; BAR; MFMA
    RD_A(a0, Ab0);
    RD_B(b0, Bbp);
    stB(nbuf, t + 1); stA(nbuf, 0, t + 1);
    asm volatile("s_waitcnt vmcnt(4)" ::: "memory");
    __builtin_amdgcn_s_barrier();
    MFMA16(a0, b0, 0, 0);

    // q1: reads h1; stage t+1 h1 (2); vmcnt(2) waits t+1's B+h0; BAR; MFMA
    RD_A(a1, Ab1);
    stA(nbuf, 1, t + 1);
    asm volatile("s_waitcnt vmcnt(2)" ::: "memory");
    __builtin_amdgcn_s_barrier();
    MFMA16(a1, b0, 4, 0);
  }
  asm volatile("s_waitcnt vmcnt(0)" ::: "memory");

#pragma unroll
  for (int mig = 0; mig < 8; ++mig)
#pragma unroll
    for (int njg = 0; njg < 2; ++njg) {
      const int row = m0 + (mig >> 2) * 128 + wm * 64 + (mig & 3) * 16 + (kg << 2);
      const int col = n0 + wn * 32 + njg * 16 + fr;
      f32x4 v = acc[mig][njg];
      if (EPI == 2) {
        float* Cf = (float*)Cout;
        const float bb = bias[col];
#pragma unroll
        for (int jj = 0; jj < 4; ++jj)
          Cf[(size_t)(row + jj) * ldc + col] = v[jj] + bb;
      } else {   // EPI == 4: bias by row (Vt-proj)
        unsigned short* Ch = (unsigned short*)Cout;
#pragma unroll
        for (int jj = 0; jj < 4; ++jj)
          Ch[(size_t)(row + jj) * ldc + col] = f2b(v[jj] + bias[row + jj]);
      }
    }
}

// -------- split-K4 reduce + normalize: attn = (P0+P1+P2+P3)/rowsum --------
__global__ __launch_bounds__(256)
void reduce_pv4(const unsigned short* __restrict__ p0,
                const unsigned short* __restrict__ p1,
                const unsigned short* __restrict__ p2,
                const unsigned short* __restrict__ p3,
                const float* __restrict__ rows,
                unsigned short* __restrict__ out) {
  const size_t i = ((size_t)blockIdx.x * 256 + threadIdx.x) << 3;
  const float inv = 1.f / rows[i >> 10];
  us8 a = *(const us8*)&p0[i];
  us8 b = *(const us8*)&p1[i];
  us8 c = *(const us8*)&p2[i];
  us8 d = *(const us8*)&p3[i];
  us8 o;
#pragma unroll
  for (int j = 0; j < 8; ++j)
    o[j] = f2b((b2f(a[j]) + b2f(b[j]) + b2f(c[j]) + b2f(d[j])) * inv);
  *(us8*)&out[i] = o;
}

// ---------------- host-side launch ----------------
extern "C" void kernel_launch(void* const* d_in, const int* in_sizes, int n_in,
                              void* d_out, int out_size, void* d_ws, size_t ws_size,
                              hipStream_t stream) {
  (void)in_sizes; (void)n_in; (void)out_size; (void)ws_size;
  const float* x  = (const float*)d_in[0];
  const float* Wq = (const float*)d_in[1];
  const float* bq = (const float*)d_in[2];
  const float* Wk = (const float*)d_in[3];
  const float* bk = (const float*)d_in[4];
  const float* Wv = (const float*)d_in[5];
  const float* bv = (const float*)d_in[6];
  const float* Wo = (const float*)d_in[7];
  const float* bo = (const float*)d_in[8];

  const int B = 4, T = 2048, C = 1024;
  const int M = B * T;                                   // 8192

  unsigned short* xb    = (unsigned short*)d_ws;         // M*C ; later P2
  unsigned short* Wqkvb = xb    + (size_t)M * C;         // [Wq|Wk|Wv]
  unsigned short* Wob   = Wqkvb + (size_t)3 * C * C;
  unsigned short* QK    = Wob   + (size_t)C * C;         // M*2C [Q|K]; later P0|P1
  unsigned short* Vt    = QK    + (size_t)M * 2 * C;     // [1024][8192]
  unsigned short* S     = Vt    + (size_t)M * C;         // B*T*T e-values
  float*          bws   = (float*)(S + (size_t)B * T * T);
  float*          rowsum= bws + 4096;                    // 8192 f32
  unsigned short* P0    = QK;                            // QK dead after scores
  unsigned short* P1    = QK + (size_t)M * C;
  unsigned short* P2    = xb;                            // xb dead after Vt-proj
  unsigned short* P3    = (unsigned short*)d_out;        // scratch pre-out-proj
  unsigned short* attn  = P0;                            // reduce writes in-place

  // 1. prep
  prep_kernel<<<12305, 256, 0, stream>>>(x, Wq, Wk, Wv, Wo, bq, bk, bv, bo,
                                         xb, Wqkvb, Wob, bws, rowsum);

  // 2a. QK projection (256 blocks)
  gemm8<3, false, false><<<dim3(2 * C / 256, M / 256, 1), 512, 0, stream>>>(
      xb, Wqkvb, QK, bws, nullptr, 1.f, C, C, C, 2 * C, 0LL, 0LL, 0LL);

  // 2b. Vt = Wv @ x^T + bv[row] (256 blocks, BN=128)
  gemm2ph<4><<<dim3(M / 128, C / 256, 1), 512, 0, stream>>>(
      Wqkvb + (size_t)2 * C * C, xb, Vt, bws + 2 * C, C, C, C, M);

  // 3. scores: S = exp(Q K^T / 32) causal-masked + rowsum atomics
  gemm8<6, false, true><<<dim3(T / 256, T / 256, B), 512, 0, stream>>>(
      QK, QK + C, S, nullptr, rowsum, 0.03125f, C, 2 * C, 2 * C, T,
      (long long)T * 2 * C, (long long)T * 2 * C, (long long)T * T);

  // 4. PV split-K=4: partials P0..P3 (z = batch*4 + quarter)
  gemm8<5, true, false><<<dim3(C / 256, T / 256, 4 * B), 512, 0, stream>>>(
      S, Vt, P0, (const float*)P2, (float*)P3, 1.f, T, T, M, C,
      (long long)T * T, 2048LL, (long long)T * C);

  // 5. reduce + normalize (attn -> P0 in place)
  reduce_pv4<<<4096, 256, 0, stream>>>(P0, P1, P2, P3, rowsum, attn);

  // 6. out = attn Wo^T + bo (f32, 256 blocks BN=128)
  gemm2ph<2><<<dim3(C / 128, M / 256, 1), 512, 0, stream>>>(
      attn, Wob, d_out, bws + 3 * C, C, C, C, C);
}